// Round 8
// baseline (41498.108 us; speedup 1.0000x reference)
//
#include <hip/hip_runtime.h>
#include <hip/hip_bf16.h>

#define NSL 64
#define NPX 16384   // 128*128
#define VN  2097152 // 128^3

// ---------------- prep: per-slice R,t (fp32 inputs) ----------------
__global__ void k_prep(const float* __restrict__ tr, const float* __restrict__ psf,
                       float* __restrict__ Rm, float* __restrict__ pw)
{
  int n = threadIdx.x;
  if (n < 27) pw[n] = psf[n];
  if (n >= NSL) return;
  #pragma unroll
  for (int i = 0; i < 3; i++){
    #pragma unroll
    for (int j = 0; j < 3; j++) Rm[n*12 + i*3 + j] = tr[n*12 + i*4 + j];
    Rm[n*12 + 9 + i] = tr[n*12 + i*4 + 3];
  }
}

// ---------------- mask ----------------
__global__ void k_mask(const float* __restrict__ slices, float* __restrict__ mask)
{
  int gid = blockIdx.x*256 + threadIdx.x;
  if (gid >= NSL*NPX) return;
  int n = gid >> 14, p = gid & 16383;
  int py = p >> 7, px = p & 127;
  const float* s = slices + n*NPX;
  bool any = false;
  for (int dy = -1; dy <= 1; dy++){
    int yy = py + dy;
    if ((unsigned)yy >= 128u) continue;
    for (int dx = -1; dx <= 1; dx++){
      int xx = px + dx;
      if ((unsigned)xx >= 128u) continue;
      any = any || (s[yy*128 + xx] > 0.f);
    }
  }
  mask[gid] = any ? 1.f : 0.f;
}

__global__ void k_volcopy(const float* __restrict__ v, float* __restrict__ o)
{
  int gid = blockIdx.x*256 + threadIdx.x;
  if (gid < VN) o[gid] = v[gid];
}

__global__ void k_copy0(const float* __restrict__ slices, float* __restrict__ z)
{
  int gid = blockIdx.x*256 + threadIdx.x;
  if (gid >= NSL*NPX) return;
  int n = gid >> 14, p = gid & 16383;
  z[n*2*NPX + p] = slices[gid];
}

// ---------------- trilinear helpers ----------------
__device__ __forceinline__ float lerpf(float a, float b, float t){ return fmaf(t, b-a, a); }

__device__ __forceinline__ float tri_gather(const float* __restrict__ vol, float x, float y, float z)
{
  float xf = floorf(x), yf = floorf(y), zf = floorf(z);
  int x0 = (int)xf, y0 = (int)yf, z0 = (int)zf;
  float fx = x - xf, fy = y - yf, fz = z - zf;
  if ((unsigned)x0 < 127u && (unsigned)y0 < 127u && (unsigned)z0 < 127u){
    const float* p = vol + (z0*128 + y0)*128 + x0;
    float c00 = lerpf(p[0],     p[1],     fx);
    float c01 = lerpf(p[128],   p[129],   fx);
    float c10 = lerpf(p[16384], p[16385], fx);
    float c11 = lerpf(p[16512], p[16513], fx);
    return lerpf(lerpf(c00, c01, fy), lerpf(c10, c11, fy), fz);
  }
  float gx0 = 1.f - fx, gy0 = 1.f - fy, gz0 = 1.f - fz;
  bool vx0 = (unsigned)x0 < 128u, vx1 = (unsigned)(x0+1) < 128u;
  bool vy0 = (unsigned)y0 < 128u, vy1 = (unsigned)(y0+1) < 128u;
  bool vz0 = (unsigned)z0 < 128u, vz1 = (unsigned)(z0+1) < 128u;
  int i0 = (z0*128 + y0)*128 + x0;
  float acc = 0.f;
  if (vz0){
    if (vy0){
      if (vx0) acc += gx0*gy0*gz0 * vol[i0];
      if (vx1) acc += fx *gy0*gz0 * vol[i0+1];
    }
    if (vy1){
      if (vx0) acc += gx0*fy*gz0 * vol[i0+128];
      if (vx1) acc += fx *fy*gz0 * vol[i0+129];
    }
  }
  if (vz1){
    int i1 = i0 + 16384;
    if (vy0){
      if (vx0) acc += gx0*gy0*fz * vol[i1];
      if (vx1) acc += fx *gy0*fz * vol[i1+1];
    }
    if (vy1){
      if (vx0) acc += gx0*fy*fz * vol[i1+128];
      if (vx1) acc += fx *fy*fz * vol[i1+129];
    }
  }
  return acc;
}

__device__ __forceinline__ void tri_scatter(float* __restrict__ vol, float x, float y, float z, float val)
{
  float xf = floorf(x), yf = floorf(y), zf = floorf(z);
  int x0 = (int)xf, y0 = (int)yf, z0 = (int)zf;
  float fx = x - xf, fy = y - yf, fz = z - zf;
  float gx0 = 1.f - fx, gy0 = 1.f - fy, gz0 = 1.f - fz;
  int i0 = (z0*128 + y0)*128 + x0;
  if ((unsigned)x0 < 127u && (unsigned)y0 < 127u && (unsigned)z0 < 127u){
    float* p = vol + i0;
    atomicAdd(p,         gx0*gy0*gz0*val);
    atomicAdd(p+1,       fx *gy0*gz0*val);
    atomicAdd(p+128,     gx0*fy*gz0*val);
    atomicAdd(p+129,     fx *fy*gz0*val);
    atomicAdd(p+16384,   gx0*gy0*fz*val);
    atomicAdd(p+16385,   fx *gy0*fz*val);
    atomicAdd(p+16512,   gx0*fy*fz*val);
    atomicAdd(p+16513,   fx *fy*fz*val);
    return;
  }
  bool vx0 = (unsigned)x0 < 128u, vx1 = (unsigned)(x0+1) < 128u;
  bool vy0 = (unsigned)y0 < 128u, vy1 = (unsigned)(y0+1) < 128u;
  bool vz0 = (unsigned)z0 < 128u, vz1 = (unsigned)(z0+1) < 128u;
  if (vz0){
    if (vy0){
      if (vx0) atomicAdd(&vol[i0],     gx0*gy0*gz0*val);
      if (vx1) atomicAdd(&vol[i0+1],   fx *gy0*gz0*val);
    }
    if (vy1){
      if (vx0) atomicAdd(&vol[i0+128], gx0*fy*gz0*val);
      if (vx1) atomicAdd(&vol[i0+129], fx *fy*gz0*val);
    }
  }
  if (vz1){
    int i1 = i0 + 16384;
    if (vy0){
      if (vx0) atomicAdd(&vol[i1],     gx0*gy0*fz*val);
      if (vx1) atomicAdd(&vol[i1+1],   fx *gy0*fz*val);
    }
    if (vy1){
      if (vx0) atomicAdd(&vol[i1+128], gx0*fy*fz*val);
      if (vx1) atomicAdd(&vol[i1+129], fx *fy*fz*val);
    }
  }
}

// ---------------- A: gather over 27 PSF taps (LDS prep + MLP) ----------------
__global__ void k_gather(const float* __restrict__ vol, const float* __restrict__ Rm,
                         const float* __restrict__ pw, const float* __restrict__ mask,
                         const float* __restrict__ ps, float* __restrict__ out,
                         int outStride, int outOff)
{
  int gid = blockIdx.x*256 + threadIdx.x;
  int n = gid >> 14;
  __shared__ float srm[12];
  __shared__ float sdof[27][3];
  __shared__ float spw[27];
  if (threadIdx.x < 12) srm[threadIdx.x] = Rm[n*12 + threadIdx.x];
  __syncthreads();
  if (threadIdx.x < 27){
    int k = threadIdx.x;
    float ox = (float)(k % 3) - 1.f;
    float oy = (float)((k/3) % 3) - 1.f;
    float oz = (float)(k/9) - 1.f;
    sdof[k][0] = srm[0]*ox + srm[1]*oy + srm[2]*oz;
    sdof[k][1] = srm[3]*ox + srm[4]*oy + srm[5]*oz;
    sdof[k][2] = srm[6]*ox + srm[7]*oy + srm[8]*oz;
    spw[k] = pw[k];
  }
  __syncthreads();
  int p = gid & 16383;
  int py = p >> 7, px = p & 127;
  float gx = (float)px - 63.5f, gy = (float)py - 63.5f;
  float bx = srm[0]*gx + srm[1]*gy + srm[9]  + 63.5f;
  float by = srm[3]*gx + srm[4]*gy + srm[10] + 63.5f;
  float bz = srm[6]*gx + srm[7]*gy + srm[11] + 63.5f;
  float acc = 0.f;
  for (int k = 0; k < 27; k += 3){
    float g0 = tri_gather(vol, bx+sdof[k  ][0], by+sdof[k  ][1], bz+sdof[k  ][2]);
    float g1 = tri_gather(vol, bx+sdof[k+1][0], by+sdof[k+1][1], bz+sdof[k+1][2]);
    float g2 = tri_gather(vol, bx+sdof[k+2][0], by+sdof[k+2][1], bz+sdof[k+2][2]);
    acc += spw[k]*g0 + spw[k+1]*g1 + spw[k+2]*g2;
  }
  float v = acc * mask[gid];
  if (ps) v *= ps[n];
  out[n*outStride + outOff + p] = v;
}

// ---------------- At: scatter (lane-interleaved pixels + LDS prep) ----------------
__global__ void k_scatter(float* __restrict__ volOut, const float* __restrict__ s,
                          const float* __restrict__ Rm, const float* __restrict__ pw,
                          const float* __restrict__ mask, const float* __restrict__ ps)
{
  int gid = blockIdx.x*256 + threadIdx.x;
  int n = gid >> 14;
  __shared__ float srm[12];
  __shared__ float sdof[27][3];
  __shared__ float spw[27];
  if (threadIdx.x < 12) srm[threadIdx.x] = Rm[n*12 + threadIdx.x];
  __syncthreads();
  if (threadIdx.x < 27){
    int k = threadIdx.x;
    float ox = (float)(k % 3) - 1.f;
    float oy = (float)((k/3) % 3) - 1.f;
    float oz = (float)(k/9) - 1.f;
    sdof[k][0] = srm[0]*ox + srm[1]*oy + srm[2]*oz;
    sdof[k][1] = srm[3]*ox + srm[4]*oy + srm[5]*oz;
    sdof[k][2] = srm[6]*ox + srm[7]*oy + srm[8]*oz;
    spw[k] = pw[k];
  }
  __syncthreads();
  int p0 = gid & 16383;
  // bijective lane interleave: adjacent lanes -> rows 2 apart (disjoint voxels)
  int p = ((p0 & 63) << 8) | (p0 >> 6);
  float val = s[n*NPX + p] * mask[n*NPX + p];
  if (ps) val *= ps[n];
  if (val == 0.f) return;
  int py = p >> 7, px = p & 127;
  float gx = (float)px - 63.5f, gy = (float)py - 63.5f;
  float bx = srm[0]*gx + srm[1]*gy + srm[9]  + 63.5f;
  float by = srm[3]*gx + srm[4]*gy + srm[10] + 63.5f;
  float bz = srm[6]*gx + srm[7]*gy + srm[11] + 63.5f;
  #pragma unroll 1
  for (int k = 0; k < 27; k++){
    tri_scatter(volOut, bx+sdof[k][0], by+sdof[k][1], bz+sdof[k][2], spw[k]*val);
  }
}

// ---------------- tiled conv (NCHW fp32, LDS-staged, vertical-quad threads) ----------
// Thread: 1x4 vertical output px (x=tx, y=tyq..tyq+3), 16 co accumulators.
// Wave reads 2x32 (TILE=32) consecutive LDS floats with odd row stride -> <=2-way.
template<int K, int S, int TILE, int CC>
__global__ __launch_bounds__(256, 2) void k_convt(
    const float* __restrict__ in, const float* __restrict__ wt,
    const float* __restrict__ res, float* __restrict__ out,
    int Cin, int Hin, int Cout, int Hout,
    int pad, int relu, int coTiles, int spTiles)
{
  constexpr int BPB  = 1024 / (TILE*TILE);
  constexpr int ITX  = (K==1) ? TILE : (TILE-1)*S + K;  // K==1: decimated tile
  constexpr int ITP  = ITX | 1;                         // odd row stride
  constexpr int KK   = K*K;
  constexpr int PERB = TILE*TILE/4;
  constexpr int RS   = (K==1) ? 1 : S;                  // staged row step per out row
  constexpr int NIN  = (CC*ITX*ITX + PERB - 1)/PERB;
  constexpr int NWT  = (16*CC*KK + 255)/256;

  __shared__ float sIn[BPB*CC*ITX*ITP];
  __shared__ float sW[CC*KK*16];

  int tid = threadIdx.x;
  int bl  = tid / PERB;
  int t2  = tid % PERB;
  int tx  = t2 % TILE;
  int tyq = (t2 / TILE) * 4;

  int bid = blockIdx.x;
  int spT = bid % spTiles; bid /= spTiles;
  int coT = bid % coTiles; bid /= coTiles;
  int b0  = bid * BPB;

  int tpr = Hout / TILE;
  int ox0 = (spT % tpr) * TILE;
  int oy0 = (spT / tpr) * TILE;
  int co0 = coT * 16;
  int ix0 = ox0*S - pad;
  int iy0 = oy0*S - pad;

  float acc[64];
  #pragma unroll
  for (int i = 0; i < 64; i++) acc[i] = 0.f;

  for (int ci0 = 0; ci0 < Cin; ci0 += CC){
    // weights: sW[(cc*KK+tap)*16 + co], co contiguous for float4 broadcast
    #pragma unroll
    for (int it = 0; it < NWT; it++){
      int i = tid + it*256;
      if (i < 16*CC*KK){
        int co = i / (CC*KK);
        int r  = i % (CC*KK);
        sW[r*16 + co] = wt[((size_t)(co0+co)*Cin + ci0 + r/KK)*KK + (r % KK)];
      }
    }
    // input tile (fully unrolled staging -> loads batched)
    #pragma unroll
    for (int it = 0; it < NIN; it++){
      int i = t2 + it*PERB;
      if (i < CC*ITX*ITX){
        int cc = i / (ITX*ITX);
        int r  = i % (ITX*ITX);
        int yy = r / ITX, xx = r % ITX;
        int gy = (K==1) ? iy0 + yy*S : iy0 + yy;
        int gx = (K==1) ? ix0 + xx*S : ix0 + xx;
        float v = 0.f;
        if ((unsigned)gy < (unsigned)Hin && (unsigned)gx < (unsigned)Hin)
          v = in[(((size_t)(b0+bl)*Cin + ci0+cc)*Hin + gy)*Hin + gx];
        sIn[((bl*CC + cc)*ITX + yy)*ITP + xx] = v;
      }
    }
    __syncthreads();

    #pragma unroll
    for (int cc = 0; cc < CC; cc++){
      const float* ip = &sIn[(bl*CC + cc)*ITX*ITP];
      #pragma unroll
      for (int ky = 0; ky < K; ky++){
        #pragma unroll
        for (int kx = 0; kx < K; kx++){
          int xi = (K==1) ? tx : tx*S + kx;
          int yb = (K==1) ? tyq : tyq*S + ky;
          float v0 = ip[(yb       )*ITP + xi];
          float v1 = ip[(yb +   RS)*ITP + xi];
          float v2 = ip[(yb + 2*RS)*ITP + xi];
          float v3 = ip[(yb + 3*RS)*ITP + xi];
          const float4* wv = (const float4*)&sW[(cc*KK + ky*K + kx)*16];
          #pragma unroll
          for (int g = 0; g < 4; g++){
            float4 w = wv[g];
            acc[(g*4+0)*4+0] += w.x*v0; acc[(g*4+0)*4+1] += w.x*v1;
            acc[(g*4+0)*4+2] += w.x*v2; acc[(g*4+0)*4+3] += w.x*v3;
            acc[(g*4+1)*4+0] += w.y*v0; acc[(g*4+1)*4+1] += w.y*v1;
            acc[(g*4+1)*4+2] += w.y*v2; acc[(g*4+1)*4+3] += w.y*v3;
            acc[(g*4+2)*4+0] += w.z*v0; acc[(g*4+2)*4+1] += w.z*v1;
            acc[(g*4+2)*4+2] += w.z*v2; acc[(g*4+2)*4+3] += w.z*v3;
            acc[(g*4+3)*4+0] += w.w*v0; acc[(g*4+3)*4+1] += w.w*v1;
            acc[(g*4+3)*4+2] += w.w*v2; acc[(g*4+3)*4+3] += w.w*v3;
          }
        }
      }
    }
    __syncthreads();
  }

  int b = b0 + bl;
  #pragma unroll
  for (int co = 0; co < 16; co++){
    size_t base = (((size_t)b*Cout + co0+co)*Hout + oy0 + tyq)*Hout + ox0 + tx;
    #pragma unroll
    for (int r = 0; r < 4; r++){
      float v = acc[co*4 + r];
      if (res) v += res[base + (size_t)r*Hout];
      if (relu) v = fmaxf(v, 0.f);
      out[base + (size_t)r*Hout] = v;
    }
  }
}

// ---------------- pool + transformer ----------------
__global__ void k_pool(const float* __restrict__ in, float* __restrict__ feat, int cnt)
{
  int gid = blockIdx.x*256 + threadIdx.x;
  if (gid >= cnt) return;
  const float* p = in + (size_t)gid*256;
  float s = 0.f;
  for (int i = 0; i < 256; i++) s += p[i];
  feat[gid] = s * (1.f/256.f);
}

__global__ void k_pe(const float* __restrict__ feat, const float* __restrict__ theta,
                     const float* __restrict__ idxin, const float* __restrict__ pos_w,
                     const float* __restrict__ pos_b, float* __restrict__ hs)
{
  int gid = blockIdx.x*256 + threadIdx.x;
  if (gid >= 64*256) return;
  int n = gid >> 8, d = gid & 255;
  float s = pos_b[d];
  #pragma unroll
  for (int j = 0; j < 6; j++) s += theta[n*6+j] * pos_w[j*256+d];
  #pragma unroll
  for (int j = 0; j < 2; j++) s += idxin[n*2+j] * pos_w[(6+j)*256+d];
  hs[gid] = feat[gid] + s;
}

__global__ void k_qkv(const float* __restrict__ hs, const float* __restrict__ wq,
                      const float* __restrict__ wk, const float* __restrict__ wv,
                      float* __restrict__ qkv)
{
  int gid = blockIdx.x*256 + threadIdx.x;
  if (gid >= 64*768) return;
  int n = gid / 768, m = gid % 768;
  int which = m >> 8, j = m & 255;
  const float* w = (which == 0) ? wq : (which == 1) ? wk : wv;
  const float* h = hs + n*256;
  float s = 0.f;
  for (int i = 0; i < 256; i++) s += h[i] * w[i*256 + j];
  qkv[which*16384 + n*256 + j] = s;
}

__global__ void k_attn(const float* __restrict__ qkv, float* __restrict__ aout)
{
  int h = blockIdx.x;
  int tid = threadIdx.x;
  __shared__ float sc[4096];
  const float* q  = qkv + h*64;
  const float* kk = qkv + 16384 + h*64;
  const float* v  = qkv + 32768 + h*64;
  for (int idx = tid; idx < 4096; idx += 256){
    int qi = idx >> 6, ki = idx & 63;
    float s = 0.f;
    for (int d = 0; d < 64; d++) s += q[qi*256+d] * kk[ki*256+d];
    sc[idx] = s * 0.125f;
  }
  __syncthreads();
  if (tid < 64){
    float mx = -1e30f;
    for (int k = 0; k < 64; k++) mx = fmaxf(mx, sc[tid*64+k]);
    float sum = 0.f;
    for (int k = 0; k < 64; k++){ float e = __expf(sc[tid*64+k]-mx); sc[tid*64+k] = e; sum += e; }
    float inv = 1.f/sum;
    for (int k = 0; k < 64; k++) sc[tid*64+k] *= inv;
  }
  __syncthreads();
  for (int idx = tid; idx < 4096; idx += 256){
    int qi = idx >> 6, d = idx & 63;
    float s = 0.f;
    for (int ki = 0; ki < 64; ki++) s += sc[qi*64+ki] * v[ki*256+d];
    aout[qi*256 + h*64 + d] = s;
  }
}

__global__ void k_proj_ln(const float* __restrict__ ain, const float* __restrict__ wo,
                          const float* __restrict__ g, const float* __restrict__ bb,
                          float* __restrict__ hs)
{
  int n = blockIdx.x, d = threadIdx.x;
  __shared__ float row[256];
  __shared__ float red[256];
  __shared__ float smean, svar;
  row[d] = ain[n*256+d];
  __syncthreads();
  float s = hs[n*256+d];
  for (int i = 0; i < 256; i++) s += row[i] * wo[i*256+d];
  red[d] = s; __syncthreads();
  for (int off = 128; off; off >>= 1){ if (d < off) red[d] += red[d+off]; __syncthreads(); }
  if (d == 0) smean = red[0] * (1.f/256.f);
  __syncthreads();
  float c = s - smean;
  red[d] = c*c; __syncthreads();
  for (int off = 128; off; off >>= 1){ if (d < off) red[d] += red[d+off]; __syncthreads(); }
  if (d == 0) svar = red[0] * (1.f/256.f);
  __syncthreads();
  hs[n*256+d] = c * rsqrtf(svar + 1e-5f) * g[d] + bb[d];
}

__global__ void k_ff1(const float* __restrict__ hs, const float* __restrict__ w,
                      const float* __restrict__ b, float* __restrict__ h1)
{
  int gid = blockIdx.x*256 + threadIdx.x;
  if (gid >= 64*512) return;
  int n = gid >> 9, j = gid & 511;
  float s = b[j];
  const float* h = hs + n*256;
  for (int i = 0; i < 256; i++) s += h[i] * w[i*512 + j];
  h1[gid] = fmaxf(s, 0.f);
}

__global__ void k_ff2_ln(const float* __restrict__ h1, const float* __restrict__ w,
                         const float* __restrict__ b, const float* __restrict__ g,
                         const float* __restrict__ bb, float* __restrict__ hs)
{
  int n = blockIdx.x, d = threadIdx.x;
  __shared__ float row[512];
  __shared__ float red[256];
  __shared__ float smean, svar;
  row[d] = h1[n*512+d];
  row[d+256] = h1[n*512+256+d];
  __syncthreads();
  float s = hs[n*256+d] + b[d];
  for (int i = 0; i < 512; i++) s += row[i] * w[i*256+d];
  red[d] = s; __syncthreads();
  for (int off = 128; off; off >>= 1){ if (d < off) red[d] += red[d+off]; __syncthreads(); }
  if (d == 0) smean = red[0] * (1.f/256.f);
  __syncthreads();
  float c = s - smean;
  red[d] = c*c; __syncthreads();
  for (int off = 128; off; off >>= 1){ if (d < off) red[d] += red[d+off]; __syncthreads(); }
  if (d == 0) svar = red[0] * (1.f/256.f);
  __syncthreads();
  hs[n*256+d] = c * rsqrtf(svar + 1e-5f) * g[d] + bb[d];
}

__global__ void k_head(const float* __restrict__ hs, const float* __restrict__ fcw,
                       const float* __restrict__ fcb, float* __restrict__ pvec,
                       float* __restrict__ outx)
{
  int n = threadIdx.x; // 64 threads
  float s = fcb[0];
  const float* h = hs + n*256;
  for (int i = 0; i < 256; i++) s += h[i] * fcw[i];
  __shared__ float xs[64];
  xs[n] = s;
  __syncthreads();
  float mx = -1e30f;
  for (int i = 0; i < 64; i++) mx = fmaxf(mx, xs[i]);
  float sum = 0.f;
  for (int i = 0; i < 64; i++) sum += __expf(xs[i]-mx);
  float val = __expf(s-mx)/sum * 64.f;
  val = fminf(val, 3.f);
  pvec[n] = val;
  outx[n] = val;
}

// ---------------- CG helpers ----------------
__global__ void k_dot(const float* __restrict__ a, const float* __restrict__ b,
                      float* __restrict__ scal, int slot, int n)
{
  int gid = blockIdx.x*blockDim.x + threadIdx.x;
  int stride = gridDim.x*blockDim.x;
  float s = 0.f;
  for (int i = gid; i < n; i += stride) s += a[i]*b[i];
  for (int off = 32; off; off >>= 1) s += __shfl_down(s, off, 64);
  __shared__ float wsum[4];
  int lane = threadIdx.x & 63, wv = threadIdx.x >> 6;
  if (lane == 0) wsum[wv] = s;
  __syncthreads();
  if (threadIdx.x == 0) atomicAdd(&scal[slot], wsum[0]+wsum[1]+wsum[2]+wsum[3]);
}

__global__ void k_div(float* scal, int so, int sa, int sb)
{
  if (threadIdx.x == 0 && blockIdx.x == 0) scal[so] = scal[sa] / scal[sb];
}

__global__ void k_rinit(const float* __restrict__ b, const float* __restrict__ A,
                        float* __restrict__ r, float* __restrict__ p)
{
  int gid = blockIdx.x*256 + threadIdx.x;
  if (gid < VN){ float v = b[gid] - A[gid]; r[gid] = v; p[gid] = v; }
}

__global__ void k_xr(float* __restrict__ x, const float* __restrict__ p,
                     float* __restrict__ r, const float* __restrict__ Ap,
                     const float* __restrict__ scal, int slot)
{
  int gid = blockIdx.x*256 + threadIdx.x;
  if (gid < VN){
    float a = scal[slot];
    x[gid] += a * p[gid];
    r[gid] -= a * Ap[gid];
  }
}

__global__ void k_pupd(float* __restrict__ p, const float* __restrict__ r,
                       const float* __restrict__ scal, int slot)
{
  int gid = blockIdx.x*256 + threadIdx.x;
  if (gid < VN){ float b = scal[slot]; p[gid] = r[gid] + b * p[gid]; }
}

__global__ void k_xonly(float* __restrict__ x, const float* __restrict__ p,
                        const float* __restrict__ scal, int slot)
{
  int gid = blockIdx.x*256 + threadIdx.x;
  if (gid < VN) x[gid] += scal[slot] * p[gid];
}

__global__ void k_final(const float* __restrict__ x, float* __restrict__ out)
{
  int gid = blockIdx.x*256 + threadIdx.x;
  if (gid < VN) out[gid] = fmaxf(x[gid], 0.f);
}

// ---------------- host launch ----------------
extern "C" void kernel_launch(void* const* d_in, const int* in_sizes, int n_in,
                              void* d_out, int out_size, void* d_ws, size_t ws_size,
                              hipStream_t stream)
{
  const float* theta      = (const float*)d_in[0];
  const float* transforms = (const float*)d_in[1];
  const float* slices     = (const float*)d_in[2];
  const float* volume     = (const float*)d_in[3];
  const float* psf        = (const float*)d_in[4];
  const float* idxv       = (const float*)d_in[5];

  char* wsp = (char*)d_ws;
  auto carve = [&](size_t bytes)->void*{
    void* r = (void*)wsp; wsp += (bytes + 255) & ~(size_t)255; return r;
  };
  float* scal = (float*)carve(16*4);
  float* Rm   = (float*)carve(768*4);
  float* pw   = (float*)carve(32*4);
  float* pvec = (float*)carve(64*4);
  float* feat = (float*)carve(16384*4);
  float* hs   = (float*)carve(16384*4);
  float* qkv  = (float*)carve(49152*4);
  float* aout = (float*)carve(16384*4);
  float* h1   = (float*)carve(32768*4);
  float* mask = (float*)carve((size_t)NSL*NPX*4);
  float* volA = (float*)carve((size_t)VN*4);

  // choose conv batch-chunk CB by available workspace (same result every call)
  size_t used  = (size_t)(wsp - (char*)d_ws);
  size_t avail = (ws_size > used) ? ws_size - used : 0;
  size_t cgU   = ((size_t)4*VN + NSL*NPX)*4;               // CG overlay requirement
  auto needU = [&](int cb)->size_t{
    size_t u = ((size_t)VN + 3*(size_t)cb*262144)*4;       // z + 3 conv bufs
    return (u > cgU) ? u : cgU;
  };
  int CB = 8;
  if (avail >= needU(64) + 4096) CB = 64;
  else if (avail >= needU(32) + 4096) CB = 32;

  size_t cbe = (size_t)CB*262144;                          // conv buffer elems per chunk
  float* U    = (float*)carve(needU(CB));
  float* z    = U;
  float* bufA = U + VN;
  float* bufB = bufA + cbe;
  float* bufC = bufB + cbe;
  float* bvol = U;
  float* rvol = U + VN;
  float* pvol = U + 2*(size_t)VN;
  float* Avol = U + 3*(size_t)VN;
  float* sscr = U + 4*(size_t)VN;

  hipMemsetAsync(scal, 0, 64, stream);
  k_prep<<<1, 64, 0, stream>>>(transforms, psf, Rm, pw);
  k_mask<<<4096, 256, 0, stream>>>(slices, mask);
  k_volcopy<<<8192, 256, 0, stream>>>(volume, volA);
  k_gather<<<4096, 256, 0, stream>>>(volA, Rm, pw, mask, nullptr, z, 2*NPX, NPX);
  k_copy0<<<4096, 256, 0, stream>>>(slices, z);

  const float* w6  = (const float*)d_in[6];
  const float* w7  = (const float*)d_in[7];
  const float* w8  = (const float*)d_in[8];
  const float* w9  = (const float*)d_in[9];
  const float* w10 = (const float*)d_in[10];
  const float* w11 = (const float*)d_in[11];
  const float* w12 = (const float*)d_in[12];
  const float* w13 = (const float*)d_in[13];
  const float* w14 = (const float*)d_in[14];

  // CNN in chunks of CB slices; tiled convs
  for (int c = 0; c < 64/CB; c++){
    const float* zc = z + (size_t)c*CB*2*NPX;
    k_convt<7,2,32,2><<<CB*16, 256, 0, stream>>>(zc,  w6,  nullptr, bufA, 2,  128, 64,  64, 2, 1, 4, 4);
    k_convt<3,1,32,4><<<CB*16, 256, 0, stream>>>(bufA, w7,  nullptr, bufB, 64, 64,  64,  64, 1, 1, 4, 4);
    k_convt<3,1,32,4><<<CB*16, 256, 0, stream>>>(bufB, w8,  bufA,    bufC, 64, 64,  64,  64, 1, 1, 4, 4);
    k_convt<3,2,32,1><<<CB*8,  256, 0, stream>>>(bufC, w9,  nullptr, bufA, 64, 64,  128, 32, 0, 1, 8, 1);
    k_convt<1,2,32,2><<<CB*8,  256, 0, stream>>>(bufC, w11, nullptr, bufB, 64, 64,  128, 32, 0, 0, 8, 1);
    k_convt<3,1,32,4><<<CB*8,  256, 0, stream>>>(bufA, w10, bufB,    bufC, 128,32,  128, 32, 1, 1, 8, 1);
    k_convt<3,2,16,2><<<(CB/4)*16, 256, 0, stream>>>(bufC, w12, nullptr, bufA, 128, 32, 256, 16, 0, 1, 16, 1);
    k_convt<1,2,16,2><<<(CB/4)*16, 256, 0, stream>>>(bufC, w14, nullptr, bufB, 128, 32, 256, 16, 0, 0, 16, 1);
    k_convt<3,1,16,4><<<(CB/4)*16, 256, 0, stream>>>(bufA, w13, bufB,    bufC, 256, 16, 256, 16, 1, 1, 16, 1);
    k_pool<<<CB, 256, 0, stream>>>(bufC, feat + (size_t)c*CB*256, CB*256);
  }

  k_pe<<<64, 256, 0, stream>>>(feat, theta, idxv, (const float*)d_in[15], (const float*)d_in[16], hs);
  for (int l = 0; l < 4; l++){
    k_qkv<<<192, 256, 0, stream>>>(hs, (const float*)d_in[17] + (size_t)l*65536,
                                       (const float*)d_in[18] + (size_t)l*65536,
                                       (const float*)d_in[19] + (size_t)l*65536, qkv);
    k_attn<<<4, 256, 0, stream>>>(qkv, aout);
    k_proj_ln<<<64, 256, 0, stream>>>(aout, (const float*)d_in[20] + (size_t)l*65536,
                                      (const float*)d_in[21] + l*256, (const float*)d_in[22] + l*256, hs);
    k_ff1<<<128, 256, 0, stream>>>(hs, (const float*)d_in[23] + (size_t)l*131072,
                                   (const float*)d_in[24] + l*512, h1);
    k_ff2_ln<<<64, 256, 0, stream>>>(h1, (const float*)d_in[25] + (size_t)l*131072,
                                     (const float*)d_in[26] + l*256, (const float*)d_in[27] + l*256,
                                     (const float*)d_in[28] + l*256, hs);
  }
  k_head<<<1, 64, 0, stream>>>(hs, (const float*)d_in[29], (const float*)d_in[30], pvec,
                               (float*)d_out + VN);

  // ---- CG (union region now CG-owned) ----
  hipMemsetAsync(bvol, 0, (size_t)VN*4, stream);
  k_scatter<<<4096, 256, 0, stream>>>(bvol, slices, Rm, pw, mask, pvec);      // b = At(slices*p)
  k_gather<<<4096, 256, 0, stream>>>(volA, Rm, pw, mask, pvec, sscr, NPX, 0); // A(x0)*mask*p
  hipMemsetAsync(Avol, 0, (size_t)VN*4, stream);
  k_scatter<<<4096, 256, 0, stream>>>(Avol, sscr, Rm, pw, mask, nullptr);     // AtA(x0)
  k_rinit<<<8192, 256, 0, stream>>>(bvol, Avol, rvol, pvol);
  k_dot<<<512, 256, 0, stream>>>(rvol, rvol, scal, 0, VN);         // rr0
  // iter 1
  k_gather<<<4096, 256, 0, stream>>>(pvol, Rm, pw, mask, pvec, sscr, NPX, 0);
  hipMemsetAsync(Avol, 0, (size_t)VN*4, stream);
  k_scatter<<<4096, 256, 0, stream>>>(Avol, sscr, Rm, pw, mask, nullptr);
  k_dot<<<512, 256, 0, stream>>>(pvol, Avol, scal, 1, VN);         // pAp1
  k_div<<<1, 1, 0, stream>>>(scal, 2, 0, 1);                       // alpha1 = rr0/pAp1
  k_xr<<<8192, 256, 0, stream>>>(volA, pvol, rvol, Avol, scal, 2);
  k_dot<<<512, 256, 0, stream>>>(rvol, rvol, scal, 3, VN);         // rr1
  k_div<<<1, 1, 0, stream>>>(scal, 4, 3, 0);                       // beta = rr1/rr0
  k_pupd<<<8192, 256, 0, stream>>>(pvol, rvol, scal, 4);
  // iter 2
  k_gather<<<4096, 256, 0, stream>>>(pvol, Rm, pw, mask, pvec, sscr, NPX, 0);
  hipMemsetAsync(Avol, 0, (size_t)VN*4, stream);
  k_scatter<<<4096, 256, 0, stream>>>(Avol, sscr, Rm, pw, mask, nullptr);
  k_dot<<<512, 256, 0, stream>>>(pvol, Avol, scal, 5, VN);         // pAp2
  k_div<<<1, 1, 0, stream>>>(scal, 6, 3, 5);                       // alpha2 = rr1/pAp2
  k_xonly<<<8192, 256, 0, stream>>>(volA, pvol, scal, 6);

  k_final<<<8192, 256, 0, stream>>>(volA, (float*)d_out);
}

// Round 9
// 10049.258 us; speedup vs baseline: 4.1295x; 4.1295x over previous
//
#include <hip/hip_runtime.h>
#include <hip/hip_bf16.h>

#define NSL 64
#define NPX 16384   // 128*128
#define VN  2097152 // 128^3
#define SCAP 12288  // LDS accumulator cap (48 KB)

// ---------------- prep: per-slice R,t (fp32 inputs) ----------------
__global__ void k_prep(const float* __restrict__ tr, const float* __restrict__ psf,
                       float* __restrict__ Rm, float* __restrict__ pw)
{
  int n = threadIdx.x;
  if (n < 27) pw[n] = psf[n];
  if (n >= NSL) return;
  #pragma unroll
  for (int i = 0; i < 3; i++){
    #pragma unroll
    for (int j = 0; j < 3; j++) Rm[n*12 + i*3 + j] = tr[n*12 + i*4 + j];
    Rm[n*12 + 9 + i] = tr[n*12 + i*4 + 3];
  }
}

// ---------------- mask ----------------
__global__ void k_mask(const float* __restrict__ slices, float* __restrict__ mask)
{
  int gid = blockIdx.x*256 + threadIdx.x;
  if (gid >= NSL*NPX) return;
  int n = gid >> 14, p = gid & 16383;
  int py = p >> 7, px = p & 127;
  const float* s = slices + n*NPX;
  bool any = false;
  for (int dy = -1; dy <= 1; dy++){
    int yy = py + dy;
    if ((unsigned)yy >= 128u) continue;
    for (int dx = -1; dx <= 1; dx++){
      int xx = px + dx;
      if ((unsigned)xx >= 128u) continue;
      any = any || (s[yy*128 + xx] > 0.f);
    }
  }
  mask[gid] = any ? 1.f : 0.f;
}

__global__ void k_volcopy(const float* __restrict__ v, float* __restrict__ o)
{
  int gid = blockIdx.x*256 + threadIdx.x;
  if (gid < VN) o[gid] = v[gid];
}

__global__ void k_copy0(const float* __restrict__ slices, float* __restrict__ z)
{
  int gid = blockIdx.x*256 + threadIdx.x;
  if (gid >= NSL*NPX) return;
  int n = gid >> 14, p = gid & 16383;
  z[n*2*NPX + p] = slices[gid];
}

// ---------------- trilinear helpers ----------------
__device__ __forceinline__ float lerpf(float a, float b, float t){ return fmaf(t, b-a, a); }

__device__ __forceinline__ float tri_gather(const float* __restrict__ vol, float x, float y, float z)
{
  float xf = floorf(x), yf = floorf(y), zf = floorf(z);
  int x0 = (int)xf, y0 = (int)yf, z0 = (int)zf;
  float fx = x - xf, fy = y - yf, fz = z - zf;
  if ((unsigned)x0 < 127u && (unsigned)y0 < 127u && (unsigned)z0 < 127u){
    const float* p = vol + (z0*128 + y0)*128 + x0;
    float c00 = lerpf(p[0],     p[1],     fx);
    float c01 = lerpf(p[128],   p[129],   fx);
    float c10 = lerpf(p[16384], p[16385], fx);
    float c11 = lerpf(p[16512], p[16513], fx);
    return lerpf(lerpf(c00, c01, fy), lerpf(c10, c11, fy), fz);
  }
  float gx0 = 1.f - fx, gy0 = 1.f - fy, gz0 = 1.f - fz;
  bool vx0 = (unsigned)x0 < 128u, vx1 = (unsigned)(x0+1) < 128u;
  bool vy0 = (unsigned)y0 < 128u, vy1 = (unsigned)(y0+1) < 128u;
  bool vz0 = (unsigned)z0 < 128u, vz1 = (unsigned)(z0+1) < 128u;
  int i0 = (z0*128 + y0)*128 + x0;
  float acc = 0.f;
  if (vz0){
    if (vy0){
      if (vx0) acc += gx0*gy0*gz0 * vol[i0];
      if (vx1) acc += fx *gy0*gz0 * vol[i0+1];
    }
    if (vy1){
      if (vx0) acc += gx0*fy*gz0 * vol[i0+128];
      if (vx1) acc += fx *fy*gz0 * vol[i0+129];
    }
  }
  if (vz1){
    int i1 = i0 + 16384;
    if (vy0){
      if (vx0) acc += gx0*gy0*fz * vol[i1];
      if (vx1) acc += fx *gy0*fz * vol[i1+1];
    }
    if (vy1){
      if (vx0) acc += gx0*fy*fz * vol[i1+128];
      if (vx1) acc += fx *fy*fz * vol[i1+129];
    }
  }
  return acc;
}

__device__ __forceinline__ void tri_scatter(float* __restrict__ vol, float x, float y, float z, float val)
{
  float xf = floorf(x), yf = floorf(y), zf = floorf(z);
  int x0 = (int)xf, y0 = (int)yf, z0 = (int)zf;
  float fx = x - xf, fy = y - yf, fz = z - zf;
  float gx0 = 1.f - fx, gy0 = 1.f - fy, gz0 = 1.f - fz;
  int i0 = (z0*128 + y0)*128 + x0;
  if ((unsigned)x0 < 127u && (unsigned)y0 < 127u && (unsigned)z0 < 127u){
    float* p = vol + i0;
    atomicAdd(p,         gx0*gy0*gz0*val);
    atomicAdd(p+1,       fx *gy0*gz0*val);
    atomicAdd(p+128,     gx0*fy*gz0*val);
    atomicAdd(p+129,     fx *fy*gz0*val);
    atomicAdd(p+16384,   gx0*gy0*fz*val);
    atomicAdd(p+16385,   fx *gy0*fz*val);
    atomicAdd(p+16512,   gx0*fy*fz*val);
    atomicAdd(p+16513,   fx *fy*fz*val);
    return;
  }
  bool vx0 = (unsigned)x0 < 128u, vx1 = (unsigned)(x0+1) < 128u;
  bool vy0 = (unsigned)y0 < 128u, vy1 = (unsigned)(y0+1) < 128u;
  bool vz0 = (unsigned)z0 < 128u, vz1 = (unsigned)(z0+1) < 128u;
  if (vz0){
    if (vy0){
      if (vx0) atomicAdd(&vol[i0],     gx0*gy0*gz0*val);
      if (vx1) atomicAdd(&vol[i0+1],   fx *gy0*gz0*val);
    }
    if (vy1){
      if (vx0) atomicAdd(&vol[i0+128], gx0*fy*gz0*val);
      if (vx1) atomicAdd(&vol[i0+129], fx *fy*gz0*val);
    }
  }
  if (vz1){
    int i1 = i0 + 16384;
    if (vy0){
      if (vx0) atomicAdd(&vol[i1],     gx0*gy0*fz*val);
      if (vx1) atomicAdd(&vol[i1+1],   fx *gy0*fz*val);
    }
    if (vy1){
      if (vx0) atomicAdd(&vol[i1+128], gx0*fy*fz*val);
      if (vx1) atomicAdd(&vol[i1+129], fx *fy*fz*val);
    }
  }
}

// ---------------- A: gather over 27 PSF taps (LDS prep + MLP) ----------------
__global__ void k_gather(const float* __restrict__ vol, const float* __restrict__ Rm,
                         const float* __restrict__ pw, const float* __restrict__ mask,
                         const float* __restrict__ ps, float* __restrict__ out,
                         int outStride, int outOff)
{
  int gid = blockIdx.x*256 + threadIdx.x;
  int n = gid >> 14;
  __shared__ float srm[12];
  __shared__ float sdof[27][3];
  __shared__ float spw[27];
  if (threadIdx.x < 12) srm[threadIdx.x] = Rm[n*12 + threadIdx.x];
  __syncthreads();
  if (threadIdx.x < 27){
    int k = threadIdx.x;
    float ox = (float)(k % 3) - 1.f;
    float oy = (float)((k/3) % 3) - 1.f;
    float oz = (float)(k/9) - 1.f;
    sdof[k][0] = srm[0]*ox + srm[1]*oy + srm[2]*oz;
    sdof[k][1] = srm[3]*ox + srm[4]*oy + srm[5]*oz;
    sdof[k][2] = srm[6]*ox + srm[7]*oy + srm[8]*oz;
    spw[k] = pw[k];
  }
  __syncthreads();
  int p = gid & 16383;
  int py = p >> 7, px = p & 127;
  float gx = (float)px - 63.5f, gy = (float)py - 63.5f;
  float bx = srm[0]*gx + srm[1]*gy + srm[9]  + 63.5f;
  float by = srm[3]*gx + srm[4]*gy + srm[10] + 63.5f;
  float bz = srm[6]*gx + srm[7]*gy + srm[11] + 63.5f;
  float acc = 0.f;
  for (int k = 0; k < 27; k += 3){
    float g0 = tri_gather(vol, bx+sdof[k  ][0], by+sdof[k  ][1], bz+sdof[k  ][2]);
    float g1 = tri_gather(vol, bx+sdof[k+1][0], by+sdof[k+1][1], bz+sdof[k+1][2]);
    float g2 = tri_gather(vol, bx+sdof[k+2][0], by+sdof[k+2][1], bz+sdof[k+2][2]);
    acc += spw[k]*g0 + spw[k+1]*g1 + spw[k+2]*g2;
  }
  float v = acc * mask[gid];
  if (ps) v *= ps[n];
  out[n*outStride + outOff + p] = v;
}

// ---------------- At: scatter v3 — LDS-privatized per 16x16-pixel patch ----------
// One block per (slice, 16x16 patch). Bounding box of all atomic targets is
// computed analytically (affine map, 4 patch corners + |R|-row extents).
// Accumulate 27x8 corner adds into LDS box (ds atomics), flush nonzero voxels
// with one global atomic each (~15x fewer global atomics, line-coalesced).
__global__ __launch_bounds__(256, 2) void k_scatterp(
    float* __restrict__ volOut, const float* __restrict__ s,
    const float* __restrict__ Rm, const float* __restrict__ pw,
    const float* __restrict__ mask, const float* __restrict__ ps)
{
  __shared__ float srm[12];
  __shared__ float sdof[27][3];
  __shared__ float spw[27];
  __shared__ float sAcc[SCAP];

  int n  = blockIdx.x >> 6;
  int pt = blockIdx.x & 63;
  int px0 = (pt & 7) * 16;
  int py0 = (pt >> 3) * 16;
  int tid = threadIdx.x;

  if (tid < 12) srm[tid] = Rm[n*12 + tid];
  __syncthreads();
  if (tid < 27){
    int k = tid;
    float ox = (float)(k % 3) - 1.f;
    float oy = (float)((k/3) % 3) - 1.f;
    float oz = (float)(k/9) - 1.f;
    sdof[k][0] = srm[0]*ox + srm[1]*oy + srm[2]*oz;
    sdof[k][1] = srm[3]*ox + srm[4]*oy + srm[5]*oz;
    sdof[k][2] = srm[6]*ox + srm[7]*oy + srm[8]*oz;
    spw[k] = pw[k];
  }
  __syncthreads();

  int px = px0 + (tid & 15);
  int py = py0 + (tid >> 4);
  int p  = py*128 + px;
  float val = s[n*NPX + p] * mask[n*NPX + p];
  if (ps) val *= ps[n];

  float gx = (float)px - 63.5f, gy = (float)py - 63.5f;
  float bx = srm[0]*gx + srm[1]*gy + srm[9]  + 63.5f;
  float by = srm[3]*gx + srm[4]*gy + srm[10] + 63.5f;
  float bz = srm[6]*gx + srm[7]*gy + srm[11] + 63.5f;

  // analytic bbox over the patch (block-uniform)
  float gxa = (float)px0 - 63.5f, gxb = (float)(px0+15) - 63.5f;
  float gya = (float)py0 - 63.5f, gyb = (float)(py0+15) - 63.5f;
  int lo[3], hi[3];
  #pragma unroll
  for (int d = 0; d < 3; d++){
    float r0 = srm[d*3+0], r1 = srm[d*3+1];
    float ext = fabsf(r0) + fabsf(r1) + fabsf(srm[d*3+2]);
    float c = srm[9+d] + 63.5f;
    float mn = c + fminf(r0*gxa, r0*gxb) + fminf(r1*gya, r1*gyb) - ext;
    float mx = c + fmaxf(r0*gxa, r0*gxb) + fmaxf(r1*gya, r1*gyb) + ext;
    int l = (int)floorf(mn), h = (int)floorf(mx) + 1;
    lo[d] = (l < 0) ? 0 : l;
    hi[d] = (h > 127) ? 127 : h;
  }
  if (hi[0] < lo[0] || hi[1] < lo[1] || hi[2] < lo[2]) return; // fully off-volume (uniform)
  int Bx = hi[0]-lo[0]+1, By = hi[1]-lo[1]+1, Bz = hi[2]-lo[2]+1;
  int vol = Bx*By*Bz;

  if (vol <= SCAP){
    for (int i = tid; i < vol; i += 256) sAcc[i] = 0.f;
    __syncthreads();
    if (val != 0.f){
      #pragma unroll 1
      for (int k = 0; k < 27; k++){
        float x = bx + sdof[k][0], y = by + sdof[k][1], z = bz + sdof[k][2];
        float xf = floorf(x), yf = floorf(y), zf = floorf(z);
        int x0 = (int)xf, y0 = (int)yf, z0 = (int)zf;
        float fx = x - xf, fy = y - yf, fz = z - zf;
        float gx0 = 1.f - fx, gy0 = 1.f - fy, gz0 = 1.f - fz;
        float v = spw[k]*val;
        int ix = x0 - lo[0], iy = y0 - lo[1], iz = z0 - lo[2];
        if (ix >= 0 && ix+1 < Bx && iy >= 0 && iy+1 < By && iz >= 0 && iz+1 < Bz){
          float* q = &sAcc[(iz*By + iy)*Bx + ix];
          atomicAdd(q,            gx0*gy0*gz0*v);
          atomicAdd(q+1,          fx *gy0*gz0*v);
          atomicAdd(q+Bx,         gx0*fy*gz0*v);
          atomicAdd(q+Bx+1,       fx *fy*gz0*v);
          atomicAdd(q+Bx*By,      gx0*gy0*fz*v);
          atomicAdd(q+Bx*By+1,    fx *gy0*fz*v);
          atomicAdd(q+Bx*By+Bx,   gx0*fy*fz*v);
          atomicAdd(q+Bx*By+Bx+1, fx *fy*fz*v);
        } else {
          // box-guard == [0,127] guard by construction
          #pragma unroll
          for (int c = 0; c < 8; c++){
            int dx = c & 1, dy = (c>>1) & 1, dz = c>>2;
            int xx = ix+dx, yy = iy+dy, zz = iz+dz;
            if ((unsigned)xx < (unsigned)Bx && (unsigned)yy < (unsigned)By && (unsigned)zz < (unsigned)Bz){
              float w = (dx ? fx : gx0) * (dy ? fy : gy0) * (dz ? fz : gz0);
              atomicAdd(&sAcc[(zz*By + yy)*Bx + xx], w*v);
            }
          }
        }
      }
    }
    __syncthreads();
    for (int i = tid; i < vol; i += 256){
      float v = sAcc[i];
      if (v != 0.f){
        int x = i % Bx, r = i / Bx;
        int y = r % By, z = r / By;
        atomicAdd(&volOut[((lo[2]+z)*128 + lo[1]+y)*128 + lo[0]+x], v);
      }
    }
  } else {
    // fallback (not expected at these rotation magnitudes)
    if (val != 0.f){
      #pragma unroll 1
      for (int k = 0; k < 27; k++)
        tri_scatter(volOut, bx+sdof[k][0], by+sdof[k][1], bz+sdof[k][2], spw[k]*val);
    }
  }
}

// ---------------- tiled conv (NCHW fp32, LDS-staged, vertical-quad threads) ----------
template<int K, int S, int TILE, int CC>
__global__ __launch_bounds__(256, 2) void k_convt(
    const float* __restrict__ in, const float* __restrict__ wt,
    const float* __restrict__ res, float* __restrict__ out,
    int Cin, int Hin, int Cout, int Hout,
    int pad, int relu, int coTiles, int spTiles)
{
  constexpr int BPB  = 1024 / (TILE*TILE);
  constexpr int ITX  = (K==1) ? TILE : (TILE-1)*S + K;
  constexpr int ITP  = ITX | 1;
  constexpr int KK   = K*K;
  constexpr int PERB = TILE*TILE/4;
  constexpr int RS   = (K==1) ? 1 : S;
  constexpr int NIN  = (CC*ITX*ITX + PERB - 1)/PERB;
  constexpr int NWT  = (16*CC*KK + 255)/256;

  __shared__ float sIn[BPB*CC*ITX*ITP];
  __shared__ float sW[CC*KK*16];

  int tid = threadIdx.x;
  int bl  = tid / PERB;
  int t2  = tid % PERB;
  int tx  = t2 % TILE;
  int tyq = (t2 / TILE) * 4;

  int bid = blockIdx.x;
  int spT = bid % spTiles; bid /= spTiles;
  int coT = bid % coTiles; bid /= coTiles;
  int b0  = bid * BPB;

  int tpr = Hout / TILE;
  int ox0 = (spT % tpr) * TILE;
  int oy0 = (spT / tpr) * TILE;
  int co0 = coT * 16;
  int ix0 = ox0*S - pad;
  int iy0 = oy0*S - pad;

  float acc[64];
  #pragma unroll
  for (int i = 0; i < 64; i++) acc[i] = 0.f;

  for (int ci0 = 0; ci0 < Cin; ci0 += CC){
    #pragma unroll
    for (int it = 0; it < NWT; it++){
      int i = tid + it*256;
      if (i < 16*CC*KK){
        int co = i / (CC*KK);
        int r  = i % (CC*KK);
        sW[r*16 + co] = wt[((size_t)(co0+co)*Cin + ci0 + r/KK)*KK + (r % KK)];
      }
    }
    #pragma unroll
    for (int it = 0; it < NIN; it++){
      int i = t2 + it*PERB;
      if (i < CC*ITX*ITX){
        int cc = i / (ITX*ITX);
        int r  = i % (ITX*ITX);
        int yy = r / ITX, xx = r % ITX;
        int gy = (K==1) ? iy0 + yy*S : iy0 + yy;
        int gx = (K==1) ? ix0 + xx*S : ix0 + xx;
        float v = 0.f;
        if ((unsigned)gy < (unsigned)Hin && (unsigned)gx < (unsigned)Hin)
          v = in[(((size_t)(b0+bl)*Cin + ci0+cc)*Hin + gy)*Hin + gx];
        sIn[((bl*CC + cc)*ITX + yy)*ITP + xx] = v;
      }
    }
    __syncthreads();

    #pragma unroll
    for (int cc = 0; cc < CC; cc++){
      const float* ip = &sIn[(bl*CC + cc)*ITX*ITP];
      #pragma unroll
      for (int ky = 0; ky < K; ky++){
        #pragma unroll
        for (int kx = 0; kx < K; kx++){
          int xi = (K==1) ? tx : tx*S + kx;
          int yb = (K==1) ? tyq : tyq*S + ky;
          float v0 = ip[(yb       )*ITP + xi];
          float v1 = ip[(yb +   RS)*ITP + xi];
          float v2 = ip[(yb + 2*RS)*ITP + xi];
          float v3 = ip[(yb + 3*RS)*ITP + xi];
          const float4* wv = (const float4*)&sW[(cc*KK + ky*K + kx)*16];
          #pragma unroll
          for (int g = 0; g < 4; g++){
            float4 w = wv[g];
            acc[(g*4+0)*4+0] += w.x*v0; acc[(g*4+0)*4+1] += w.x*v1;
            acc[(g*4+0)*4+2] += w.x*v2; acc[(g*4+0)*4+3] += w.x*v3;
            acc[(g*4+1)*4+0] += w.y*v0; acc[(g*4+1)*4+1] += w.y*v1;
            acc[(g*4+1)*4+2] += w.y*v2; acc[(g*4+1)*4+3] += w.y*v3;
            acc[(g*4+2)*4+0] += w.z*v0; acc[(g*4+2)*4+1] += w.z*v1;
            acc[(g*4+2)*4+2] += w.z*v2; acc[(g*4+2)*4+3] += w.z*v3;
            acc[(g*4+3)*4+0] += w.w*v0; acc[(g*4+3)*4+1] += w.w*v1;
            acc[(g*4+3)*4+2] += w.w*v2; acc[(g*4+3)*4+3] += w.w*v3;
          }
        }
      }
    }
    __syncthreads();
  }

  int b = b0 + bl;
  #pragma unroll
  for (int co = 0; co < 16; co++){
    size_t base = (((size_t)b*Cout + co0+co)*Hout + oy0 + tyq)*Hout + ox0 + tx;
    #pragma unroll
    for (int r = 0; r < 4; r++){
      float v = acc[co*4 + r];
      if (res) v += res[base + (size_t)r*Hout];
      if (relu) v = fmaxf(v, 0.f);
      out[base + (size_t)r*Hout] = v;
    }
  }
}

// ---------------- pool + transformer ----------------
__global__ void k_pool(const float* __restrict__ in, float* __restrict__ feat, int cnt)
{
  int gid = blockIdx.x*256 + threadIdx.x;
  if (gid >= cnt) return;
  const float* p = in + (size_t)gid*256;
  float s = 0.f;
  for (int i = 0; i < 256; i++) s += p[i];
  feat[gid] = s * (1.f/256.f);
}

__global__ void k_pe(const float* __restrict__ feat, const float* __restrict__ theta,
                     const float* __restrict__ idxin, const float* __restrict__ pos_w,
                     const float* __restrict__ pos_b, float* __restrict__ hs)
{
  int gid = blockIdx.x*256 + threadIdx.x;
  if (gid >= 64*256) return;
  int n = gid >> 8, d = gid & 255;
  float s = pos_b[d];
  #pragma unroll
  for (int j = 0; j < 6; j++) s += theta[n*6+j] * pos_w[j*256+d];
  #pragma unroll
  for (int j = 0; j < 2; j++) s += idxin[n*2+j] * pos_w[(6+j)*256+d];
  hs[gid] = feat[gid] + s;
}

__global__ void k_qkv(const float* __restrict__ hs, const float* __restrict__ wq,
                      const float* __restrict__ wk, const float* __restrict__ wv,
                      float* __restrict__ qkv)
{
  int gid = blockIdx.x*256 + threadIdx.x;
  if (gid >= 64*768) return;
  int n = gid / 768, m = gid % 768;
  int which = m >> 8, j = m & 255;
  const float* w = (which == 0) ? wq : (which == 1) ? wk : wv;
  const float* h = hs + n*256;
  float s = 0.f;
  for (int i = 0; i < 256; i++) s += h[i] * w[i*256 + j];
  qkv[which*16384 + n*256 + j] = s;
}

__global__ void k_attn(const float* __restrict__ qkv, float* __restrict__ aout)
{
  int h = blockIdx.x;
  int tid = threadIdx.x;
  __shared__ float sc[4096];
  const float* q  = qkv + h*64;
  const float* kk = qkv + 16384 + h*64;
  const float* v  = qkv + 32768 + h*64;
  for (int idx = tid; idx < 4096; idx += 256){
    int qi = idx >> 6, ki = idx & 63;
    float s = 0.f;
    for (int d = 0; d < 64; d++) s += q[qi*256+d] * kk[ki*256+d];
    sc[idx] = s * 0.125f;
  }
  __syncthreads();
  if (tid < 64){
    float mx = -1e30f;
    for (int k = 0; k < 64; k++) mx = fmaxf(mx, sc[tid*64+k]);
    float sum = 0.f;
    for (int k = 0; k < 64; k++){ float e = __expf(sc[tid*64+k]-mx); sc[tid*64+k] = e; sum += e; }
    float inv = 1.f/sum;
    for (int k = 0; k < 64; k++) sc[tid*64+k] *= inv;
  }
  __syncthreads();
  for (int idx = tid; idx < 4096; idx += 256){
    int qi = idx >> 6, d = idx & 63;
    float s = 0.f;
    for (int ki = 0; ki < 64; ki++) s += sc[qi*64+ki] * v[ki*256+d];
    aout[qi*256 + h*64 + d] = s;
  }
}

__global__ void k_proj_ln(const float* __restrict__ ain, const float* __restrict__ wo,
                          const float* __restrict__ g, const float* __restrict__ bb,
                          float* __restrict__ hs)
{
  int n = blockIdx.x, d = threadIdx.x;
  __shared__ float row[256];
  __shared__ float red[256];
  __shared__ float smean, svar;
  row[d] = ain[n*256+d];
  __syncthreads();
  float s = hs[n*256+d];
  for (int i = 0; i < 256; i++) s += row[i] * wo[i*256+d];
  red[d] = s; __syncthreads();
  for (int off = 128; off; off >>= 1){ if (d < off) red[d] += red[d+off]; __syncthreads(); }
  if (d == 0) smean = red[0] * (1.f/256.f);
  __syncthreads();
  float c = s - smean;
  red[d] = c*c; __syncthreads();
  for (int off = 128; off; off >>= 1){ if (d < off) red[d] += red[d+off]; __syncthreads(); }
  if (d == 0) svar = red[0] * (1.f/256.f);
  __syncthreads();
  hs[n*256+d] = c * rsqrtf(svar + 1e-5f) * g[d] + bb[d];
}

__global__ void k_ff1(const float* __restrict__ hs, const float* __restrict__ w,
                      const float* __restrict__ b, float* __restrict__ h1)
{
  int gid = blockIdx.x*256 + threadIdx.x;
  if (gid >= 64*512) return;
  int n = gid >> 9, j = gid & 511;
  float s = b[j];
  const float* h = hs + n*256;
  for (int i = 0; i < 256; i++) s += h[i] * w[i*512 + j];
  h1[gid] = fmaxf(s, 0.f);
}

__global__ void k_ff2_ln(const float* __restrict__ h1, const float* __restrict__ w,
                         const float* __restrict__ b, const float* __restrict__ g,
                         const float* __restrict__ bb, float* __restrict__ hs)
{
  int n = blockIdx.x, d = threadIdx.x;
  __shared__ float row[512];
  __shared__ float red[256];
  __shared__ float smean, svar;
  row[d] = h1[n*512+d];
  row[d+256] = h1[n*512+256+d];
  __syncthreads();
  float s = hs[n*256+d] + b[d];
  for (int i = 0; i < 512; i++) s += row[i] * w[i*256+d];
  red[d] = s; __syncthreads();
  for (int off = 128; off; off >>= 1){ if (d < off) red[d] += red[d+off]; __syncthreads(); }
  if (d == 0) smean = red[0] * (1.f/256.f);
  __syncthreads();
  float c = s - smean;
  red[d] = c*c; __syncthreads();
  for (int off = 128; off; off >>= 1){ if (d < off) red[d] += red[d+off]; __syncthreads(); }
  if (d == 0) svar = red[0] * (1.f/256.f);
  __syncthreads();
  hs[n*256+d] = c * rsqrtf(svar + 1e-5f) * g[d] + bb[d];
}

__global__ void k_head(const float* __restrict__ hs, const float* __restrict__ fcw,
                       const float* __restrict__ fcb, float* __restrict__ pvec,
                       float* __restrict__ outx)
{
  int n = threadIdx.x; // 64 threads
  float s = fcb[0];
  const float* h = hs + n*256;
  for (int i = 0; i < 256; i++) s += h[i] * fcw[i];
  __shared__ float xs[64];
  xs[n] = s;
  __syncthreads();
  float mx = -1e30f;
  for (int i = 0; i < 64; i++) mx = fmaxf(mx, xs[i]);
  float sum = 0.f;
  for (int i = 0; i < 64; i++) sum += __expf(xs[i]-mx);
  float val = __expf(s-mx)/sum * 64.f;
  val = fminf(val, 3.f);
  pvec[n] = val;
  outx[n] = val;
}

// ---------------- CG helpers ----------------
__global__ void k_dot(const float* __restrict__ a, const float* __restrict__ b,
                      float* __restrict__ scal, int slot, int n)
{
  int gid = blockIdx.x*blockDim.x + threadIdx.x;
  int stride = gridDim.x*blockDim.x;
  float s = 0.f;
  for (int i = gid; i < n; i += stride) s += a[i]*b[i];
  for (int off = 32; off; off >>= 1) s += __shfl_down(s, off, 64);
  __shared__ float wsum[4];
  int lane = threadIdx.x & 63, wv = threadIdx.x >> 6;
  if (lane == 0) wsum[wv] = s;
  __syncthreads();
  if (threadIdx.x == 0) atomicAdd(&scal[slot], wsum[0]+wsum[1]+wsum[2]+wsum[3]);
}

__global__ void k_div(float* scal, int so, int sa, int sb)
{
  if (threadIdx.x == 0 && blockIdx.x == 0) scal[so] = scal[sa] / scal[sb];
}

__global__ void k_rinit(const float* __restrict__ b, const float* __restrict__ A,
                        float* __restrict__ r, float* __restrict__ p)
{
  int gid = blockIdx.x*256 + threadIdx.x;
  if (gid < VN){ float v = b[gid] - A[gid]; r[gid] = v; p[gid] = v; }
}

__global__ void k_xr(float* __restrict__ x, const float* __restrict__ p,
                     float* __restrict__ r, const float* __restrict__ Ap,
                     const float* __restrict__ scal, int slot)
{
  int gid = blockIdx.x*256 + threadIdx.x;
  if (gid < VN){
    float a = scal[slot];
    x[gid] += a * p[gid];
    r[gid] -= a * Ap[gid];
  }
}

__global__ void k_pupd(float* __restrict__ p, const float* __restrict__ r,
                       const float* __restrict__ scal, int slot)
{
  int gid = blockIdx.x*256 + threadIdx.x;
  if (gid < VN){ float b = scal[slot]; p[gid] = r[gid] + b * p[gid]; }
}

__global__ void k_xonly(float* __restrict__ x, const float* __restrict__ p,
                        const float* __restrict__ scal, int slot)
{
  int gid = blockIdx.x*256 + threadIdx.x;
  if (gid < VN) x[gid] += scal[slot] * p[gid];
}

__global__ void k_final(const float* __restrict__ x, float* __restrict__ out)
{
  int gid = blockIdx.x*256 + threadIdx.x;
  if (gid < VN) out[gid] = fmaxf(x[gid], 0.f);
}

// ---------------- host launch ----------------
extern "C" void kernel_launch(void* const* d_in, const int* in_sizes, int n_in,
                              void* d_out, int out_size, void* d_ws, size_t ws_size,
                              hipStream_t stream)
{
  const float* theta      = (const float*)d_in[0];
  const float* transforms = (const float*)d_in[1];
  const float* slices     = (const float*)d_in[2];
  const float* volume     = (const float*)d_in[3];
  const float* psf        = (const float*)d_in[4];
  const float* idxv       = (const float*)d_in[5];

  char* wsp = (char*)d_ws;
  auto carve = [&](size_t bytes)->void*{
    void* r = (void*)wsp; wsp += (bytes + 255) & ~(size_t)255; return r;
  };
  float* scal = (float*)carve(16*4);
  float* Rm   = (float*)carve(768*4);
  float* pw   = (float*)carve(32*4);
  float* pvec = (float*)carve(64*4);
  float* feat = (float*)carve(16384*4);
  float* hs   = (float*)carve(16384*4);
  float* qkv  = (float*)carve(49152*4);
  float* aout = (float*)carve(16384*4);
  float* h1   = (float*)carve(32768*4);
  float* mask = (float*)carve((size_t)NSL*NPX*4);
  float* volA = (float*)carve((size_t)VN*4);

  // choose conv batch-chunk CB by available workspace (same result every call)
  size_t used  = (size_t)(wsp - (char*)d_ws);
  size_t avail = (ws_size > used) ? ws_size - used : 0;
  size_t cgU   = ((size_t)4*VN + NSL*NPX)*4;
  auto needU = [&](int cb)->size_t{
    size_t u = ((size_t)VN + 3*(size_t)cb*262144)*4;
    return (u > cgU) ? u : cgU;
  };
  int CB = 8;
  if (avail >= needU(64) + 4096) CB = 64;
  else if (avail >= needU(32) + 4096) CB = 32;

  size_t cbe = (size_t)CB*262144;
  float* U    = (float*)carve(needU(CB));
  float* z    = U;
  float* bufA = U + VN;
  float* bufB = bufA + cbe;
  float* bufC = bufB + cbe;
  float* bvol = U;
  float* rvol = U + VN;
  float* pvol = U + 2*(size_t)VN;
  float* Avol = U + 3*(size_t)VN;
  float* sscr = U + 4*(size_t)VN;

  hipMemsetAsync(scal, 0, 64, stream);
  k_prep<<<1, 64, 0, stream>>>(transforms, psf, Rm, pw);
  k_mask<<<4096, 256, 0, stream>>>(slices, mask);
  k_volcopy<<<8192, 256, 0, stream>>>(volume, volA);
  k_gather<<<4096, 256, 0, stream>>>(volA, Rm, pw, mask, nullptr, z, 2*NPX, NPX);
  k_copy0<<<4096, 256, 0, stream>>>(slices, z);

  const float* w6  = (const float*)d_in[6];
  const float* w7  = (const float*)d_in[7];
  const float* w8  = (const float*)d_in[8];
  const float* w9  = (const float*)d_in[9];
  const float* w10 = (const float*)d_in[10];
  const float* w11 = (const float*)d_in[11];
  const float* w12 = (const float*)d_in[12];
  const float* w13 = (const float*)d_in[13];
  const float* w14 = (const float*)d_in[14];

  for (int c = 0; c < 64/CB; c++){
    const float* zc = z + (size_t)c*CB*2*NPX;
    k_convt<7,2,32,2><<<CB*16, 256, 0, stream>>>(zc,  w6,  nullptr, bufA, 2,  128, 64,  64, 2, 1, 4, 4);
    k_convt<3,1,32,4><<<CB*16, 256, 0, stream>>>(bufA, w7,  nullptr, bufB, 64, 64,  64,  64, 1, 1, 4, 4);
    k_convt<3,1,32,4><<<CB*16, 256, 0, stream>>>(bufB, w8,  bufA,    bufC, 64, 64,  64,  64, 1, 1, 4, 4);
    k_convt<3,2,32,1><<<CB*8,  256, 0, stream>>>(bufC, w9,  nullptr, bufA, 64, 64,  128, 32, 0, 1, 8, 1);
    k_convt<1,2,32,2><<<CB*8,  256, 0, stream>>>(bufC, w11, nullptr, bufB, 64, 64,  128, 32, 0, 0, 8, 1);
    k_convt<3,1,32,4><<<CB*8,  256, 0, stream>>>(bufA, w10, bufB,    bufC, 128,32,  128, 32, 1, 1, 8, 1);
    k_convt<3,2,16,2><<<(CB/4)*16, 256, 0, stream>>>(bufC, w12, nullptr, bufA, 128, 32, 256, 16, 0, 1, 16, 1);
    k_convt<1,2,16,2><<<(CB/4)*16, 256, 0, stream>>>(bufC, w14, nullptr, bufB, 128, 32, 256, 16, 0, 0, 16, 1);
    k_convt<3,1,16,4><<<(CB/4)*16, 256, 0, stream>>>(bufA, w13, bufB,    bufC, 256, 16, 256, 16, 1, 1, 16, 1);
    k_pool<<<CB, 256, 0, stream>>>(bufC, feat + (size_t)c*CB*256, CB*256);
  }

  k_pe<<<64, 256, 0, stream>>>(feat, theta, idxv, (const float*)d_in[15], (const float*)d_in[16], hs);
  for (int l = 0; l < 4; l++){
    k_qkv<<<192, 256, 0, stream>>>(hs, (const float*)d_in[17] + (size_t)l*65536,
                                       (const float*)d_in[18] + (size_t)l*65536,
                                       (const float*)d_in[19] + (size_t)l*65536, qkv);
    k_attn<<<4, 256, 0, stream>>>(qkv, aout);
    k_proj_ln<<<64, 256, 0, stream>>>(aout, (const float*)d_in[20] + (size_t)l*65536,
                                      (const float*)d_in[21] + l*256, (const float*)d_in[22] + l*256, hs);
    k_ff1<<<128, 256, 0, stream>>>(hs, (const float*)d_in[23] + (size_t)l*131072,
                                   (const float*)d_in[24] + l*512, h1);
    k_ff2_ln<<<64, 256, 0, stream>>>(h1, (const float*)d_in[25] + (size_t)l*131072,
                                     (const float*)d_in[26] + l*256, (const float*)d_in[27] + l*256,
                                     (const float*)d_in[28] + l*256, hs);
  }
  k_head<<<1, 64, 0, stream>>>(hs, (const float*)d_in[29], (const float*)d_in[30], pvec,
                               (float*)d_out + VN);

  // ---- CG (union region now CG-owned) ----
  hipMemsetAsync(bvol, 0, (size_t)VN*4, stream);
  k_scatterp<<<4096, 256, 0, stream>>>(bvol, slices, Rm, pw, mask, pvec);      // b = At(slices*p)
  k_gather<<<4096, 256, 0, stream>>>(volA, Rm, pw, mask, pvec, sscr, NPX, 0);  // A(x0)*mask*p
  hipMemsetAsync(Avol, 0, (size_t)VN*4, stream);
  k_scatterp<<<4096, 256, 0, stream>>>(Avol, sscr, Rm, pw, mask, nullptr);     // AtA(x0)
  k_rinit<<<8192, 256, 0, stream>>>(bvol, Avol, rvol, pvol);
  k_dot<<<512, 256, 0, stream>>>(rvol, rvol, scal, 0, VN);         // rr0
  // iter 1
  k_gather<<<4096, 256, 0, stream>>>(pvol, Rm, pw, mask, pvec, sscr, NPX, 0);
  hipMemsetAsync(Avol, 0, (size_t)VN*4, stream);
  k_scatterp<<<4096, 256, 0, stream>>>(Avol, sscr, Rm, pw, mask, nullptr);
  k_dot<<<512, 256, 0, stream>>>(pvol, Avol, scal, 1, VN);         // pAp1
  k_div<<<1, 1, 0, stream>>>(scal, 2, 0, 1);                       // alpha1 = rr0/pAp1
  k_xr<<<8192, 256, 0, stream>>>(volA, pvol, rvol, Avol, scal, 2);
  k_dot<<<512, 256, 0, stream>>>(rvol, rvol, scal, 3, VN);         // rr1
  k_div<<<1, 1, 0, stream>>>(scal, 4, 3, 0);                       // beta = rr1/rr0
  k_pupd<<<8192, 256, 0, stream>>>(pvol, rvol, scal, 4);
  // iter 2
  k_gather<<<4096, 256, 0, stream>>>(pvol, Rm, pw, mask, pvec, sscr, NPX, 0);
  hipMemsetAsync(Avol, 0, (size_t)VN*4, stream);
  k_scatterp<<<4096, 256, 0, stream>>>(Avol, sscr, Rm, pw, mask, nullptr);
  k_dot<<<512, 256, 0, stream>>>(pvol, Avol, scal, 5, VN);         // pAp2
  k_div<<<1, 1, 0, stream>>>(scal, 6, 3, 5);                       // alpha2 = rr1/pAp2
  k_xonly<<<8192, 256, 0, stream>>>(volA, pvol, scal, 6);

  k_final<<<8192, 256, 0, stream>>>(volA, (float*)d_out);
}

// Round 10
// 9854.399 us; speedup vs baseline: 4.2111x; 1.0198x over previous
//
#include <hip/hip_runtime.h>
#include <hip/hip_bf16.h>

#define NSL 64
#define NPX 16384   // 128*128
#define VN  2097152 // 128^3
#define SCAP 12288  // LDS accumulator cap (48 KB)

// ---------------- prep: per-slice R,t (fp32 inputs) ----------------
__global__ void k_prep(const float* __restrict__ tr, const float* __restrict__ psf,
                       float* __restrict__ Rm, float* __restrict__ pw)
{
  int n = threadIdx.x;
  if (n < 27) pw[n] = psf[n];
  if (n >= NSL) return;
  #pragma unroll
  for (int i = 0; i < 3; i++){
    #pragma unroll
    for (int j = 0; j < 3; j++) Rm[n*12 + i*3 + j] = tr[n*12 + i*4 + j];
    Rm[n*12 + 9 + i] = tr[n*12 + i*4 + 3];
  }
}

// ---------------- mask ----------------
__global__ void k_mask(const float* __restrict__ slices, float* __restrict__ mask)
{
  int gid = blockIdx.x*256 + threadIdx.x;
  if (gid >= NSL*NPX) return;
  int n = gid >> 14, p = gid & 16383;
  int py = p >> 7, px = p & 127;
  const float* s = slices + n*NPX;
  bool any = false;
  for (int dy = -1; dy <= 1; dy++){
    int yy = py + dy;
    if ((unsigned)yy >= 128u) continue;
    for (int dx = -1; dx <= 1; dx++){
      int xx = px + dx;
      if ((unsigned)xx >= 128u) continue;
      any = any || (s[yy*128 + xx] > 0.f);
    }
  }
  mask[gid] = any ? 1.f : 0.f;
}

__global__ void k_volcopy(const float* __restrict__ v, float* __restrict__ o)
{
  int gid = blockIdx.x*256 + threadIdx.x;
  if (gid < VN) o[gid] = v[gid];
}

__global__ void k_copy0(const float* __restrict__ slices, float* __restrict__ z)
{
  int gid = blockIdx.x*256 + threadIdx.x;
  if (gid >= NSL*NPX) return;
  int n = gid >> 14, p = gid & 16383;
  z[n*2*NPX + p] = slices[gid];
}

// ---------------- trilinear helpers ----------------
__device__ __forceinline__ float lerpf(float a, float b, float t){ return fmaf(t, b-a, a); }

__device__ __forceinline__ float tri_gather(const float* __restrict__ vol, float x, float y, float z)
{
  float xf = floorf(x), yf = floorf(y), zf = floorf(z);
  int x0 = (int)xf, y0 = (int)yf, z0 = (int)zf;
  float fx = x - xf, fy = y - yf, fz = z - zf;
  if ((unsigned)x0 < 127u && (unsigned)y0 < 127u && (unsigned)z0 < 127u){
    const float* p = vol + (z0*128 + y0)*128 + x0;
    float c00 = lerpf(p[0],     p[1],     fx);
    float c01 = lerpf(p[128],   p[129],   fx);
    float c10 = lerpf(p[16384], p[16385], fx);
    float c11 = lerpf(p[16512], p[16513], fx);
    return lerpf(lerpf(c00, c01, fy), lerpf(c10, c11, fy), fz);
  }
  float gx0 = 1.f - fx, gy0 = 1.f - fy, gz0 = 1.f - fz;
  bool vx0 = (unsigned)x0 < 128u, vx1 = (unsigned)(x0+1) < 128u;
  bool vy0 = (unsigned)y0 < 128u, vy1 = (unsigned)(y0+1) < 128u;
  bool vz0 = (unsigned)z0 < 128u, vz1 = (unsigned)(z0+1) < 128u;
  int i0 = (z0*128 + y0)*128 + x0;
  float acc = 0.f;
  if (vz0){
    if (vy0){
      if (vx0) acc += gx0*gy0*gz0 * vol[i0];
      if (vx1) acc += fx *gy0*gz0 * vol[i0+1];
    }
    if (vy1){
      if (vx0) acc += gx0*fy*gz0 * vol[i0+128];
      if (vx1) acc += fx *fy*gz0 * vol[i0+129];
    }
  }
  if (vz1){
    int i1 = i0 + 16384;
    if (vy0){
      if (vx0) acc += gx0*gy0*fz * vol[i1];
      if (vx1) acc += fx *gy0*fz * vol[i1+1];
    }
    if (vy1){
      if (vx0) acc += gx0*fy*fz * vol[i1+128];
      if (vx1) acc += fx *fy*fz * vol[i1+129];
    }
  }
  return acc;
}

__device__ __forceinline__ void tri_scatter(float* __restrict__ vol, float x, float y, float z, float val)
{
  float xf = floorf(x), yf = floorf(y), zf = floorf(z);
  int x0 = (int)xf, y0 = (int)yf, z0 = (int)zf;
  float fx = x - xf, fy = y - yf, fz = z - zf;
  float gx0 = 1.f - fx, gy0 = 1.f - fy, gz0 = 1.f - fz;
  int i0 = (z0*128 + y0)*128 + x0;
  if ((unsigned)x0 < 127u && (unsigned)y0 < 127u && (unsigned)z0 < 127u){
    float* p = vol + i0;
    atomicAdd(p,         gx0*gy0*gz0*val);
    atomicAdd(p+1,       fx *gy0*gz0*val);
    atomicAdd(p+128,     gx0*fy*gz0*val);
    atomicAdd(p+129,     fx *fy*gz0*val);
    atomicAdd(p+16384,   gx0*gy0*fz*val);
    atomicAdd(p+16385,   fx *gy0*fz*val);
    atomicAdd(p+16512,   gx0*fy*fz*val);
    atomicAdd(p+16513,   fx *fy*fz*val);
    return;
  }
  bool vx0 = (unsigned)x0 < 128u, vx1 = (unsigned)(x0+1) < 128u;
  bool vy0 = (unsigned)y0 < 128u, vy1 = (unsigned)(y0+1) < 128u;
  bool vz0 = (unsigned)z0 < 128u, vz1 = (unsigned)(z0+1) < 128u;
  if (vz0){
    if (vy0){
      if (vx0) atomicAdd(&vol[i0],     gx0*gy0*gz0*val);
      if (vx1) atomicAdd(&vol[i0+1],   fx *gy0*gz0*val);
    }
    if (vy1){
      if (vx0) atomicAdd(&vol[i0+128], gx0*fy*gz0*val);
      if (vx1) atomicAdd(&vol[i0+129], fx *fy*gz0*val);
    }
  }
  if (vz1){
    int i1 = i0 + 16384;
    if (vy0){
      if (vx0) atomicAdd(&vol[i1],     gx0*gy0*fz*val);
      if (vx1) atomicAdd(&vol[i1+1],   fx *gy0*fz*val);
    }
    if (vy1){
      if (vx0) atomicAdd(&vol[i1+128], gx0*fy*fz*val);
      if (vx1) atomicAdd(&vol[i1+129], fx *fy*fz*val);
    }
  }
}

// ---------------- A: gather over 27 PSF taps (LDS prep + MLP) ----------------
__global__ void k_gather(const float* __restrict__ vol, const float* __restrict__ Rm,
                         const float* __restrict__ pw, const float* __restrict__ mask,
                         const float* __restrict__ ps, float* __restrict__ out,
                         int outStride, int outOff)
{
  int gid = blockIdx.x*256 + threadIdx.x;
  int n = gid >> 14;
  __shared__ float srm[12];
  __shared__ float sdof[27][3];
  __shared__ float spw[27];
  if (threadIdx.x < 12) srm[threadIdx.x] = Rm[n*12 + threadIdx.x];
  __syncthreads();
  if (threadIdx.x < 27){
    int k = threadIdx.x;
    float ox = (float)(k % 3) - 1.f;
    float oy = (float)((k/3) % 3) - 1.f;
    float oz = (float)(k/9) - 1.f;
    sdof[k][0] = srm[0]*ox + srm[1]*oy + srm[2]*oz;
    sdof[k][1] = srm[3]*ox + srm[4]*oy + srm[5]*oz;
    sdof[k][2] = srm[6]*ox + srm[7]*oy + srm[8]*oz;
    spw[k] = pw[k];
  }
  __syncthreads();
  int p = gid & 16383;
  int py = p >> 7, px = p & 127;
  float gx = (float)px - 63.5f, gy = (float)py - 63.5f;
  float bx = srm[0]*gx + srm[1]*gy + srm[9]  + 63.5f;
  float by = srm[3]*gx + srm[4]*gy + srm[10] + 63.5f;
  float bz = srm[6]*gx + srm[7]*gy + srm[11] + 63.5f;
  float acc = 0.f;
  for (int k = 0; k < 27; k += 3){
    float g0 = tri_gather(vol, bx+sdof[k  ][0], by+sdof[k  ][1], bz+sdof[k  ][2]);
    float g1 = tri_gather(vol, bx+sdof[k+1][0], by+sdof[k+1][1], bz+sdof[k+1][2]);
    float g2 = tri_gather(vol, bx+sdof[k+2][0], by+sdof[k+2][1], bz+sdof[k+2][2]);
    acc += spw[k]*g0 + spw[k+1]*g1 + spw[k+2]*g2;
  }
  float v = acc * mask[gid];
  if (ps) v *= ps[n];
  out[n*outStride + outOff + p] = v;
}

// ---------------- At: scatter v3 — LDS-privatized per 16x16-pixel patch ----------
__global__ __launch_bounds__(256, 2) void k_scatterp(
    float* __restrict__ volOut, const float* __restrict__ s,
    const float* __restrict__ Rm, const float* __restrict__ pw,
    const float* __restrict__ mask, const float* __restrict__ ps)
{
  __shared__ float srm[12];
  __shared__ float sdof[27][3];
  __shared__ float spw[27];
  __shared__ float sAcc[SCAP];

  int n  = blockIdx.x >> 6;
  int pt = blockIdx.x & 63;
  int px0 = (pt & 7) * 16;
  int py0 = (pt >> 3) * 16;
  int tid = threadIdx.x;

  if (tid < 12) srm[tid] = Rm[n*12 + tid];
  __syncthreads();
  if (tid < 27){
    int k = tid;
    float ox = (float)(k % 3) - 1.f;
    float oy = (float)((k/3) % 3) - 1.f;
    float oz = (float)(k/9) - 1.f;
    sdof[k][0] = srm[0]*ox + srm[1]*oy + srm[2]*oz;
    sdof[k][1] = srm[3]*ox + srm[4]*oy + srm[5]*oz;
    sdof[k][2] = srm[6]*ox + srm[7]*oy + srm[8]*oz;
    spw[k] = pw[k];
  }
  __syncthreads();

  int px = px0 + (tid & 15);
  int py = py0 + (tid >> 4);
  int p  = py*128 + px;
  float val = s[n*NPX + p] * mask[n*NPX + p];
  if (ps) val *= ps[n];

  float gx = (float)px - 63.5f, gy = (float)py - 63.5f;
  float bx = srm[0]*gx + srm[1]*gy + srm[9]  + 63.5f;
  float by = srm[3]*gx + srm[4]*gy + srm[10] + 63.5f;
  float bz = srm[6]*gx + srm[7]*gy + srm[11] + 63.5f;

  float gxa = (float)px0 - 63.5f, gxb = (float)(px0+15) - 63.5f;
  float gya = (float)py0 - 63.5f, gyb = (float)(py0+15) - 63.5f;
  int lo[3], hi[3];
  #pragma unroll
  for (int d = 0; d < 3; d++){
    float r0 = srm[d*3+0], r1 = srm[d*3+1];
    float ext = fabsf(r0) + fabsf(r1) + fabsf(srm[d*3+2]);
    float c = srm[9+d] + 63.5f;
    float mn = c + fminf(r0*gxa, r0*gxb) + fminf(r1*gya, r1*gyb) - ext;
    float mx = c + fmaxf(r0*gxa, r0*gxb) + fmaxf(r1*gya, r1*gyb) + ext;
    int l = (int)floorf(mn), h = (int)floorf(mx) + 1;
    lo[d] = (l < 0) ? 0 : l;
    hi[d] = (h > 127) ? 127 : h;
  }
  if (hi[0] < lo[0] || hi[1] < lo[1] || hi[2] < lo[2]) return;
  int Bx = hi[0]-lo[0]+1, By = hi[1]-lo[1]+1, Bz = hi[2]-lo[2]+1;
  int vol = Bx*By*Bz;

  if (vol <= SCAP){
    for (int i = tid; i < vol; i += 256) sAcc[i] = 0.f;
    __syncthreads();
    if (val != 0.f){
      #pragma unroll 1
      for (int k = 0; k < 27; k++){
        float x = bx + sdof[k][0], y = by + sdof[k][1], z = bz + sdof[k][2];
        float xf = floorf(x), yf = floorf(y), zf = floorf(z);
        int x0 = (int)xf, y0 = (int)yf, z0 = (int)zf;
        float fx = x - xf, fy = y - yf, fz = z - zf;
        float gx0 = 1.f - fx, gy0 = 1.f - fy, gz0 = 1.f - fz;
        float v = spw[k]*val;
        int ix = x0 - lo[0], iy = y0 - lo[1], iz = z0 - lo[2];
        if (ix >= 0 && ix+1 < Bx && iy >= 0 && iy+1 < By && iz >= 0 && iz+1 < Bz){
          float* q = &sAcc[(iz*By + iy)*Bx + ix];
          atomicAdd(q,            gx0*gy0*gz0*v);
          atomicAdd(q+1,          fx *gy0*gz0*v);
          atomicAdd(q+Bx,         gx0*fy*gz0*v);
          atomicAdd(q+Bx+1,       fx *fy*gz0*v);
          atomicAdd(q+Bx*By,      gx0*gy0*fz*v);
          atomicAdd(q+Bx*By+1,    fx *gy0*fz*v);
          atomicAdd(q+Bx*By+Bx,   gx0*fy*fz*v);
          atomicAdd(q+Bx*By+Bx+1, fx *fy*fz*v);
        } else {
          #pragma unroll
          for (int c = 0; c < 8; c++){
            int dx = c & 1, dy = (c>>1) & 1, dz = c>>2;
            int xx = ix+dx, yy = iy+dy, zz = iz+dz;
            if ((unsigned)xx < (unsigned)Bx && (unsigned)yy < (unsigned)By && (unsigned)zz < (unsigned)Bz){
              float w = (dx ? fx : gx0) * (dy ? fy : gy0) * (dz ? fz : gz0);
              atomicAdd(&sAcc[(zz*By + yy)*Bx + xx], w*v);
            }
          }
        }
      }
    }
    __syncthreads();
    for (int i = tid; i < vol; i += 256){
      float v = sAcc[i];
      if (v != 0.f){
        int x = i % Bx, r = i / Bx;
        int y = r % By, z = r / By;
        atomicAdd(&volOut[((lo[2]+z)*128 + lo[1]+y)*128 + lo[0]+x], v);
      }
    }
  } else {
    if (val != 0.f){
      #pragma unroll 1
      for (int k = 0; k < 27; k++)
        tri_scatter(volOut, bx+sdof[k][0], by+sdof[k][1], bz+sdof[k][2], spw[k]*val);
    }
  }
}

// ---------------- tiled conv (NCHW fp32, LDS-staged, vertical-quad threads) ----------
// Block decode: spT (fast) -> batch-group (mid) -> coT (SLOW).  Same-batch
// co-tiles differ by spTiles*nBG (multiple of 8 for all 9 convs) => land on the
// SAME XCD => input slab is fetched once into that XCD's L2 and reused by all
// co-tiles (fixes the 11x HBM re-fetch seen in r9: FETCH 357MB vs 33.5MB unique).
template<int K, int S, int TILE, int CC>
__global__ __launch_bounds__(256, 2) void k_convt(
    const float* __restrict__ in, const float* __restrict__ wt,
    const float* __restrict__ res, float* __restrict__ out,
    int Cin, int Hin, int Cout, int Hout,
    int pad, int relu, int nBG, int spTiles)
{
  constexpr int BPB  = 1024 / (TILE*TILE);
  constexpr int ITX  = (K==1) ? TILE : (TILE-1)*S + K;
  constexpr int ITP  = ITX | 1;
  constexpr int KK   = K*K;
  constexpr int PERB = TILE*TILE/4;
  constexpr int RS   = (K==1) ? 1 : S;
  constexpr int NIN  = (CC*ITX*ITX + PERB - 1)/PERB;
  constexpr int NWT  = (16*CC*KK + 255)/256;

  __shared__ float sIn[BPB*CC*ITX*ITP];
  __shared__ float sW[CC*KK*16];

  int tid = threadIdx.x;
  int bl  = tid / PERB;
  int t2  = tid % PERB;
  int tx  = t2 % TILE;
  int tyq = (t2 / TILE) * 4;

  int bid = blockIdx.x;
  int spT = bid % spTiles; bid /= spTiles;
  int bG  = bid % nBG;     bid /= nBG;
  int coT = bid;
  int b0  = bG * BPB;

  int tpr = Hout / TILE;
  int ox0 = (spT % tpr) * TILE;
  int oy0 = (spT / tpr) * TILE;
  int co0 = coT * 16;
  int ix0 = ox0*S - pad;
  int iy0 = oy0*S - pad;

  float acc[64];
  #pragma unroll
  for (int i = 0; i < 64; i++) acc[i] = 0.f;

  for (int ci0 = 0; ci0 < Cin; ci0 += CC){
    #pragma unroll
    for (int it = 0; it < NWT; it++){
      int i = tid + it*256;
      if (i < 16*CC*KK){
        int co = i / (CC*KK);
        int r  = i % (CC*KK);
        sW[r*16 + co] = wt[((size_t)(co0+co)*Cin + ci0 + r/KK)*KK + (r % KK)];
      }
    }
    #pragma unroll
    for (int it = 0; it < NIN; it++){
      int i = t2 + it*PERB;
      if (i < CC*ITX*ITX){
        int cc = i / (ITX*ITX);
        int r  = i % (ITX*ITX);
        int yy = r / ITX, xx = r % ITX;
        int gy = (K==1) ? iy0 + yy*S : iy0 + yy;
        int gx = (K==1) ? ix0 + xx*S : ix0 + xx;
        float v = 0.f;
        if ((unsigned)gy < (unsigned)Hin && (unsigned)gx < (unsigned)Hin)
          v = in[(((size_t)(b0+bl)*Cin + ci0+cc)*Hin + gy)*Hin + gx];
        sIn[((bl*CC + cc)*ITX + yy)*ITP + xx] = v;
      }
    }
    __syncthreads();

    #pragma unroll
    for (int cc = 0; cc < CC; cc++){
      const float* ip = &sIn[(bl*CC + cc)*ITX*ITP];
      #pragma unroll
      for (int ky = 0; ky < K; ky++){
        #pragma unroll
        for (int kx = 0; kx < K; kx++){
          int xi = (K==1) ? tx : tx*S + kx;
          int yb = (K==1) ? tyq : tyq*S + ky;
          float v0 = ip[(yb       )*ITP + xi];
          float v1 = ip[(yb +   RS)*ITP + xi];
          float v2 = ip[(yb + 2*RS)*ITP + xi];
          float v3 = ip[(yb + 3*RS)*ITP + xi];
          const float4* wv = (const float4*)&sW[(cc*KK + ky*K + kx)*16];
          #pragma unroll
          for (int g = 0; g < 4; g++){
            float4 w = wv[g];
            acc[(g*4+0)*4+0] += w.x*v0; acc[(g*4+0)*4+1] += w.x*v1;
            acc[(g*4+0)*4+2] += w.x*v2; acc[(g*4+0)*4+3] += w.x*v3;
            acc[(g*4+1)*4+0] += w.y*v0; acc[(g*4+1)*4+1] += w.y*v1;
            acc[(g*4+1)*4+2] += w.y*v2; acc[(g*4+1)*4+3] += w.y*v3;
            acc[(g*4+2)*4+0] += w.z*v0; acc[(g*4+2)*4+1] += w.z*v1;
            acc[(g*4+2)*4+2] += w.z*v2; acc[(g*4+2)*4+3] += w.z*v3;
            acc[(g*4+3)*4+0] += w.w*v0; acc[(g*4+3)*4+1] += w.w*v1;
            acc[(g*4+3)*4+2] += w.w*v2; acc[(g*4+3)*4+3] += w.w*v3;
          }
        }
      }
    }
    __syncthreads();
  }

  int b = b0 + bl;
  #pragma unroll
  for (int co = 0; co < 16; co++){
    size_t base = (((size_t)b*Cout + co0+co)*Hout + oy0 + tyq)*Hout + ox0 + tx;
    #pragma unroll
    for (int r = 0; r < 4; r++){
      float v = acc[co*4 + r];
      if (res) v += res[base + (size_t)r*Hout];
      if (relu) v = fmaxf(v, 0.f);
      out[base + (size_t)r*Hout] = v;
    }
  }
}

// ---------------- pool + transformer ----------------
__global__ void k_pool(const float* __restrict__ in, float* __restrict__ feat, int cnt)
{
  int gid = blockIdx.x*256 + threadIdx.x;
  if (gid >= cnt) return;
  const float* p = in + (size_t)gid*256;
  float s = 0.f;
  for (int i = 0; i < 256; i++) s += p[i];
  feat[gid] = s * (1.f/256.f);
}

__global__ void k_pe(const float* __restrict__ feat, const float* __restrict__ theta,
                     const float* __restrict__ idxin, const float* __restrict__ pos_w,
                     const float* __restrict__ pos_b, float* __restrict__ hs)
{
  int gid = blockIdx.x*256 + threadIdx.x;
  if (gid >= 64*256) return;
  int n = gid >> 8, d = gid & 255;
  float s = pos_b[d];
  #pragma unroll
  for (int j = 0; j < 6; j++) s += theta[n*6+j] * pos_w[j*256+d];
  #pragma unroll
  for (int j = 0; j < 2; j++) s += idxin[n*2+j] * pos_w[(6+j)*256+d];
  hs[gid] = feat[gid] + s;
}

__global__ void k_qkv(const float* __restrict__ hs, const float* __restrict__ wq,
                      const float* __restrict__ wk, const float* __restrict__ wv,
                      float* __restrict__ qkv)
{
  int gid = blockIdx.x*256 + threadIdx.x;
  if (gid >= 64*768) return;
  int n = gid / 768, m = gid % 768;
  int which = m >> 8, j = m & 255;
  const float* w = (which == 0) ? wq : (which == 1) ? wk : wv;
  const float* h = hs + n*256;
  float s = 0.f;
  for (int i = 0; i < 256; i++) s += h[i] * w[i*256 + j];
  qkv[which*16384 + n*256 + j] = s;
}

__global__ void k_attn(const float* __restrict__ qkv, float* __restrict__ aout)
{
  int h = blockIdx.x;
  int tid = threadIdx.x;
  __shared__ float sc[4096];
  const float* q  = qkv + h*64;
  const float* kk = qkv + 16384 + h*64;
  const float* v  = qkv + 32768 + h*64;
  for (int idx = tid; idx < 4096; idx += 256){
    int qi = idx >> 6, ki = idx & 63;
    float s = 0.f;
    for (int d = 0; d < 64; d++) s += q[qi*256+d] * kk[ki*256+d];
    sc[idx] = s * 0.125f;
  }
  __syncthreads();
  if (tid < 64){
    float mx = -1e30f;
    for (int k = 0; k < 64; k++) mx = fmaxf(mx, sc[tid*64+k]);
    float sum = 0.f;
    for (int k = 0; k < 64; k++){ float e = __expf(sc[tid*64+k]-mx); sc[tid*64+k] = e; sum += e; }
    float inv = 1.f/sum;
    for (int k = 0; k < 64; k++) sc[tid*64+k] *= inv;
  }
  __syncthreads();
  for (int idx = tid; idx < 4096; idx += 256){
    int qi = idx >> 6, d = idx & 63;
    float s = 0.f;
    for (int ki = 0; ki < 64; ki++) s += sc[qi*64+ki] * v[ki*256+d];
    aout[qi*256 + h*64 + d] = s;
  }
}

__global__ void k_proj_ln(const float* __restrict__ ain, const float* __restrict__ wo,
                          const float* __restrict__ g, const float* __restrict__ bb,
                          float* __restrict__ hs)
{
  int n = blockIdx.x, d = threadIdx.x;
  __shared__ float row[256];
  __shared__ float red[256];
  __shared__ float smean, svar;
  row[d] = ain[n*256+d];
  __syncthreads();
  float s = hs[n*256+d];
  for (int i = 0; i < 256; i++) s += row[i] * wo[i*256+d];
  red[d] = s; __syncthreads();
  for (int off = 128; off; off >>= 1){ if (d < off) red[d] += red[d+off]; __syncthreads(); }
  if (d == 0) smean = red[0] * (1.f/256.f);
  __syncthreads();
  float c = s - smean;
  red[d] = c*c; __syncthreads();
  for (int off = 128; off; off >>= 1){ if (d < off) red[d] += red[d+off]; __syncthreads(); }
  if (d == 0) svar = red[0] * (1.f/256.f);
  __syncthreads();
  hs[n*256+d] = c * rsqrtf(svar + 1e-5f) * g[d] + bb[d];
}

__global__ void k_ff1(const float* __restrict__ hs, const float* __restrict__ w,
                      const float* __restrict__ b, float* __restrict__ h1)
{
  int gid = blockIdx.x*256 + threadIdx.x;
  if (gid >= 64*512) return;
  int n = gid >> 9, j = gid & 511;
  float s = b[j];
  const float* h = hs + n*256;
  for (int i = 0; i < 256; i++) s += h[i] * w[i*512 + j];
  h1[gid] = fmaxf(s, 0.f);
}

__global__ void k_ff2_ln(const float* __restrict__ h1, const float* __restrict__ w,
                         const float* __restrict__ b, const float* __restrict__ g,
                         const float* __restrict__ bb, float* __restrict__ hs)
{
  int n = blockIdx.x, d = threadIdx.x;
  __shared__ float row[512];
  __shared__ float red[256];
  __shared__ float smean, svar;
  row[d] = h1[n*512+d];
  row[d+256] = h1[n*512+256+d];
  __syncthreads();
  float s = hs[n*256+d] + b[d];
  for (int i = 0; i < 512; i++) s += row[i] * w[i*256+d];
  red[d] = s; __syncthreads();
  for (int off = 128; off; off >>= 1){ if (d < off) red[d] += red[d+off]; __syncthreads(); }
  if (d == 0) smean = red[0] * (1.f/256.f);
  __syncthreads();
  float c = s - smean;
  red[d] = c*c; __syncthreads();
  for (int off = 128; off; off >>= 1){ if (d < off) red[d] += red[d+off]; __syncthreads(); }
  if (d == 0) svar = red[0] * (1.f/256.f);
  __syncthreads();
  hs[n*256+d] = c * rsqrtf(svar + 1e-5f) * g[d] + bb[d];
}

__global__ void k_head(const float* __restrict__ hs, const float* __restrict__ fcw,
                       const float* __restrict__ fcb, float* __restrict__ pvec,
                       float* __restrict__ outx)
{
  int n = threadIdx.x; // 64 threads
  float s = fcb[0];
  const float* h = hs + n*256;
  for (int i = 0; i < 256; i++) s += h[i] * fcw[i];
  __shared__ float xs[64];
  xs[n] = s;
  __syncthreads();
  float mx = -1e30f;
  for (int i = 0; i < 64; i++) mx = fmaxf(mx, xs[i]);
  float sum = 0.f;
  for (int i = 0; i < 64; i++) sum += __expf(xs[i]-mx);
  float val = __expf(s-mx)/sum * 64.f;
  val = fminf(val, 3.f);
  pvec[n] = val;
  outx[n] = val;
}

// ---------------- CG helpers ----------------
__global__ void k_dot(const float* __restrict__ a, const float* __restrict__ b,
                      float* __restrict__ scal, int slot, int n)
{
  int gid = blockIdx.x*blockDim.x + threadIdx.x;
  int stride = gridDim.x*blockDim.x;
  float s = 0.f;
  for (int i = gid; i < n; i += stride) s += a[i]*b[i];
  for (int off = 32; off; off >>= 1) s += __shfl_down(s, off, 64);
  __shared__ float wsum[4];
  int lane = threadIdx.x & 63, wv = threadIdx.x >> 6;
  if (lane == 0) wsum[wv] = s;
  __syncthreads();
  if (threadIdx.x == 0) atomicAdd(&scal[slot], wsum[0]+wsum[1]+wsum[2]+wsum[3]);
}

__global__ void k_div(float* scal, int so, int sa, int sb)
{
  if (threadIdx.x == 0 && blockIdx.x == 0) scal[so] = scal[sa] / scal[sb];
}

__global__ void k_rinit(const float* __restrict__ b, const float* __restrict__ A,
                        float* __restrict__ r, float* __restrict__ p)
{
  int gid = blockIdx.x*256 + threadIdx.x;
  if (gid < VN){ float v = b[gid] - A[gid]; r[gid] = v; p[gid] = v; }
}

__global__ void k_xr(float* __restrict__ x, const float* __restrict__ p,
                     float* __restrict__ r, const float* __restrict__ Ap,
                     const float* __restrict__ scal, int slot)
{
  int gid = blockIdx.x*256 + threadIdx.x;
  if (gid < VN){
    float a = scal[slot];
    x[gid] += a * p[gid];
    r[gid] -= a * Ap[gid];
  }
}

__global__ void k_pupd(float* __restrict__ p, const float* __restrict__ r,
                       const float* __restrict__ scal, int slot)
{
  int gid = blockIdx.x*256 + threadIdx.x;
  if (gid < VN){ float b = scal[slot]; p[gid] = r[gid] + b * p[gid]; }
}

__global__ void k_xonly(float* __restrict__ x, const float* __restrict__ p,
                        const float* __restrict__ scal, int slot)
{
  int gid = blockIdx.x*256 + threadIdx.x;
  if (gid < VN) x[gid] += scal[slot] * p[gid];
}

__global__ void k_final(const float* __restrict__ x, float* __restrict__ out)
{
  int gid = blockIdx.x*256 + threadIdx.x;
  if (gid < VN) out[gid] = fmaxf(x[gid], 0.f);
}

// ---------------- host launch ----------------
extern "C" void kernel_launch(void* const* d_in, const int* in_sizes, int n_in,
                              void* d_out, int out_size, void* d_ws, size_t ws_size,
                              hipStream_t stream)
{
  const float* theta      = (const float*)d_in[0];
  const float* transforms = (const float*)d_in[1];
  const float* slices     = (const float*)d_in[2];
  const float* volume     = (const float*)d_in[3];
  const float* psf        = (const float*)d_in[4];
  const float* idxv       = (const float*)d_in[5];

  char* wsp = (char*)d_ws;
  auto carve = [&](size_t bytes)->void*{
    void* r = (void*)wsp; wsp += (bytes + 255) & ~(size_t)255; return r;
  };
  float* scal = (float*)carve(16*4);
  float* Rm   = (float*)carve(768*4);
  float* pw   = (float*)carve(32*4);
  float* pvec = (float*)carve(64*4);
  float* feat = (float*)carve(16384*4);
  float* hs   = (float*)carve(16384*4);
  float* qkv  = (float*)carve(49152*4);
  float* aout = (float*)carve(16384*4);
  float* h1   = (float*)carve(32768*4);
  float* mask = (float*)carve((size_t)NSL*NPX*4);
  float* volA = (float*)carve((size_t)VN*4);

  size_t used  = (size_t)(wsp - (char*)d_ws);
  size_t avail = (ws_size > used) ? ws_size - used : 0;
  size_t cgU   = ((size_t)4*VN + NSL*NPX)*4;
  auto needU = [&](int cb)->size_t{
    size_t u = ((size_t)VN + 3*(size_t)cb*262144)*4;
    return (u > cgU) ? u : cgU;
  };
  int CB = 8;
  if (avail >= needU(64) + 4096) CB = 64;
  else if (avail >= needU(32) + 4096) CB = 32;

  size_t cbe = (size_t)CB*262144;
  float* U    = (float*)carve(needU(CB));
  float* z    = U;
  float* bufA = U + VN;
  float* bufB = bufA + cbe;
  float* bufC = bufB + cbe;
  float* bvol = U;
  float* rvol = U + VN;
  float* pvol = U + 2*(size_t)VN;
  float* Avol = U + 3*(size_t)VN;
  float* sscr = U + 4*(size_t)VN;

  hipMemsetAsync(scal, 0, 64, stream);
  k_prep<<<1, 64, 0, stream>>>(transforms, psf, Rm, pw);
  k_mask<<<4096, 256, 0, stream>>>(slices, mask);
  k_volcopy<<<8192, 256, 0, stream>>>(volume, volA);
  k_gather<<<4096, 256, 0, stream>>>(volA, Rm, pw, mask, nullptr, z, 2*NPX, NPX);
  k_copy0<<<4096, 256, 0, stream>>>(slices, z);

  const float* w6  = (const float*)d_in[6];
  const float* w7  = (const float*)d_in[7];
  const float* w8  = (const float*)d_in[8];
  const float* w9  = (const float*)d_in[9];
  const float* w10 = (const float*)d_in[10];
  const float* w11 = (const float*)d_in[11];
  const float* w12 = (const float*)d_in[12];
  const float* w13 = (const float*)d_in[13];
  const float* w14 = (const float*)d_in[14];

  for (int c = 0; c < 64/CB; c++){
    const float* zc = z + (size_t)c*CB*2*NPX;
    // args: ..., nBG, spTiles   (grid = spTiles * nBG * coTiles, decode spT fast, coT slow)
    k_convt<7,2,32,2><<<CB*16, 256, 0, stream>>>(zc,  w6,  nullptr, bufA, 2,  128, 64,  64, 2, 1, CB, 4);
    k_convt<3,1,32,4><<<CB*16, 256, 0, stream>>>(bufA, w7,  nullptr, bufB, 64, 64,  64,  64, 1, 1, CB, 4);
    k_convt<3,1,32,4><<<CB*16, 256, 0, stream>>>(bufB, w8,  bufA,    bufC, 64, 64,  64,  64, 1, 1, CB, 4);
    k_convt<3,2,32,1><<<CB*8,  256, 0, stream>>>(bufC, w9,  nullptr, bufA, 64, 64,  128, 32, 0, 1, CB, 1);
    k_convt<1,2,32,2><<<CB*8,  256, 0, stream>>>(bufC, w11, nullptr, bufB, 64, 64,  128, 32, 0, 0, CB, 1);
    k_convt<3,1,32,4><<<CB*8,  256, 0, stream>>>(bufA, w10, bufB,    bufC, 128,32,  128, 32, 1, 1, CB, 1);
    k_convt<3,2,16,2><<<(CB/4)*16, 256, 0, stream>>>(bufC, w12, nullptr, bufA, 128, 32, 256, 16, 0, 1, CB/4, 1);
    k_convt<1,2,16,2><<<(CB/4)*16, 256, 0, stream>>>(bufC, w14, nullptr, bufB, 128, 32, 256, 16, 0, 0, CB/4, 1);
    k_convt<3,1,16,4><<<(CB/4)*16, 256, 0, stream>>>(bufA, w13, bufB,    bufC, 256, 16, 256, 16, 1, 1, CB/4, 1);
    k_pool<<<CB, 256, 0, stream>>>(bufC, feat + (size_t)c*CB*256, CB*256);
  }

  k_pe<<<64, 256, 0, stream>>>(feat, theta, idxv, (const float*)d_in[15], (const float*)d_in[16], hs);
  for (int l = 0; l < 4; l++){
    k_qkv<<<192, 256, 0, stream>>>(hs, (const float*)d_in[17] + (size_t)l*65536,
                                       (const float*)d_in[18] + (size_t)l*65536,
                                       (const float*)d_in[19] + (size_t)l*65536, qkv);
    k_attn<<<4, 256, 0, stream>>>(qkv, aout);
    k_proj_ln<<<64, 256, 0, stream>>>(aout, (const float*)d_in[20] + (size_t)l*65536,
                                      (const float*)d_in[21] + l*256, (const float*)d_in[22] + l*256, hs);
    k_ff1<<<128, 256, 0, stream>>>(hs, (const float*)d_in[23] + (size_t)l*131072,
                                   (const float*)d_in[24] + l*512, h1);
    k_ff2_ln<<<64, 256, 0, stream>>>(h1, (const float*)d_in[25] + (size_t)l*131072,
                                     (const float*)d_in[26] + l*256, (const float*)d_in[27] + l*256,
                                     (const float*)d_in[28] + l*256, hs);
  }
  k_head<<<1, 64, 0, stream>>>(hs, (const float*)d_in[29], (const float*)d_in[30], pvec,
                               (float*)d_out + VN);

  // ---- CG (union region now CG-owned) ----
  hipMemsetAsync(bvol, 0, (size_t)VN*4, stream);
  k_scatterp<<<4096, 256, 0, stream>>>(bvol, slices, Rm, pw, mask, pvec);      // b = At(slices*p)
  k_gather<<<4096, 256, 0, stream>>>(volA, Rm, pw, mask, pvec, sscr, NPX, 0);  // A(x0)*mask*p
  hipMemsetAsync(Avol, 0, (size_t)VN*4, stream);
  k_scatterp<<<4096, 256, 0, stream>>>(Avol, sscr, Rm, pw, mask, nullptr);     // AtA(x0)
  k_rinit<<<8192, 256, 0, stream>>>(bvol, Avol, rvol, pvol);
  k_dot<<<512, 256, 0, stream>>>(rvol, rvol, scal, 0, VN);         // rr0
  // iter 1
  k_gather<<<4096, 256, 0, stream>>>(pvol, Rm, pw, mask, pvec, sscr, NPX, 0);
  hipMemsetAsync(Avol, 0, (size_t)VN*4, stream);
  k_scatterp<<<4096, 256, 0, stream>>>(Avol, sscr, Rm, pw, mask, nullptr);
  k_dot<<<512, 256, 0, stream>>>(pvol, Avol, scal, 1, VN);         // pAp1
  k_div<<<1, 1, 0, stream>>>(scal, 2, 0, 1);                       // alpha1 = rr0/pAp1
  k_xr<<<8192, 256, 0, stream>>>(volA, pvol, rvol, Avol, scal, 2);
  k_dot<<<512, 256, 0, stream>>>(rvol, rvol, scal, 3, VN);         // rr1
  k_div<<<1, 1, 0, stream>>>(scal, 4, 3, 0);                       // beta = rr1/rr0
  k_pupd<<<8192, 256, 0, stream>>>(pvol, rvol, scal, 4);
  // iter 2
  k_gather<<<4096, 256, 0, stream>>>(pvol, Rm, pw, mask, pvec, sscr, NPX, 0);
  hipMemsetAsync(Avol, 0, (size_t)VN*4, stream);
  k_scatterp<<<4096, 256, 0, stream>>>(Avol, sscr, Rm, pw, mask, nullptr);
  k_dot<<<512, 256, 0, stream>>>(pvol, Avol, scal, 5, VN);         // pAp2
  k_div<<<1, 1, 0, stream>>>(scal, 6, 3, 5);                       // alpha2 = rr1/pAp2
  k_xonly<<<8192, 256, 0, stream>>>(volA, pvol, scal, 6);

  k_final<<<8192, 256, 0, stream>>>(volA, (float*)d_out);
}

// Round 11
// 9786.196 us; speedup vs baseline: 4.2405x; 1.0070x over previous
//
#include <hip/hip_runtime.h>
#include <hip/hip_bf16.h>

#define NSL 64
#define NPX 16384   // 128*128
#define VN  2097152 // 128^3
#define SCAP 12288  // LDS accumulator cap (48 KB)

// HW fp atomics (ds_add_f32 / global_atomic_add_f32) — no CAS loop.
__device__ __forceinline__ void fadd(float* p, float v){ unsafeAtomicAdd(p, v); }

// ---------------- prep: per-slice R,t (fp32 inputs) ----------------
__global__ void k_prep(const float* __restrict__ tr, const float* __restrict__ psf,
                       float* __restrict__ Rm, float* __restrict__ pw)
{
  int n = threadIdx.x;
  if (n < 27) pw[n] = psf[n];
  if (n >= NSL) return;
  #pragma unroll
  for (int i = 0; i < 3; i++){
    #pragma unroll
    for (int j = 0; j < 3; j++) Rm[n*12 + i*3 + j] = tr[n*12 + i*4 + j];
    Rm[n*12 + 9 + i] = tr[n*12 + i*4 + 3];
  }
}

// ---------------- mask ----------------
__global__ void k_mask(const float* __restrict__ slices, float* __restrict__ mask)
{
  int gid = blockIdx.x*256 + threadIdx.x;
  if (gid >= NSL*NPX) return;
  int n = gid >> 14, p = gid & 16383;
  int py = p >> 7, px = p & 127;
  const float* s = slices + n*NPX;
  bool any = false;
  for (int dy = -1; dy <= 1; dy++){
    int yy = py + dy;
    if ((unsigned)yy >= 128u) continue;
    for (int dx = -1; dx <= 1; dx++){
      int xx = px + dx;
      if ((unsigned)xx >= 128u) continue;
      any = any || (s[yy*128 + xx] > 0.f);
    }
  }
  mask[gid] = any ? 1.f : 0.f;
}

__global__ void k_volcopy(const float* __restrict__ v, float* __restrict__ o)
{
  int gid = blockIdx.x*256 + threadIdx.x;
  if (gid < VN) o[gid] = v[gid];
}

__global__ void k_copy0(const float* __restrict__ slices, float* __restrict__ z)
{
  int gid = blockIdx.x*256 + threadIdx.x;
  if (gid >= NSL*NPX) return;
  int n = gid >> 14, p = gid & 16383;
  z[n*2*NPX + p] = slices[gid];
}

// ---------------- trilinear helpers ----------------
__device__ __forceinline__ float lerpf(float a, float b, float t){ return fmaf(t, b-a, a); }

__device__ __forceinline__ float tri_gather(const float* __restrict__ vol, float x, float y, float z)
{
  float xf = floorf(x), yf = floorf(y), zf = floorf(z);
  int x0 = (int)xf, y0 = (int)yf, z0 = (int)zf;
  float fx = x - xf, fy = y - yf, fz = z - zf;
  if ((unsigned)x0 < 127u && (unsigned)y0 < 127u && (unsigned)z0 < 127u){
    const float* p = vol + (z0*128 + y0)*128 + x0;
    float c00 = lerpf(p[0],     p[1],     fx);
    float c01 = lerpf(p[128],   p[129],   fx);
    float c10 = lerpf(p[16384], p[16385], fx);
    float c11 = lerpf(p[16512], p[16513], fx);
    return lerpf(lerpf(c00, c01, fy), lerpf(c10, c11, fy), fz);
  }
  float gx0 = 1.f - fx, gy0 = 1.f - fy, gz0 = 1.f - fz;
  bool vx0 = (unsigned)x0 < 128u, vx1 = (unsigned)(x0+1) < 128u;
  bool vy0 = (unsigned)y0 < 128u, vy1 = (unsigned)(y0+1) < 128u;
  bool vz0 = (unsigned)z0 < 128u, vz1 = (unsigned)(z0+1) < 128u;
  int i0 = (z0*128 + y0)*128 + x0;
  float acc = 0.f;
  if (vz0){
    if (vy0){
      if (vx0) acc += gx0*gy0*gz0 * vol[i0];
      if (vx1) acc += fx *gy0*gz0 * vol[i0+1];
    }
    if (vy1){
      if (vx0) acc += gx0*fy*gz0 * vol[i0+128];
      if (vx1) acc += fx *fy*gz0 * vol[i0+129];
    }
  }
  if (vz1){
    int i1 = i0 + 16384;
    if (vy0){
      if (vx0) acc += gx0*gy0*fz * vol[i1];
      if (vx1) acc += fx *gy0*fz * vol[i1+1];
    }
    if (vy1){
      if (vx0) acc += gx0*fy*fz * vol[i1+128];
      if (vx1) acc += fx *fy*fz * vol[i1+129];
    }
  }
  return acc;
}

__device__ __forceinline__ void tri_scatter(float* __restrict__ vol, float x, float y, float z, float val)
{
  float xf = floorf(x), yf = floorf(y), zf = floorf(z);
  int x0 = (int)xf, y0 = (int)yf, z0 = (int)zf;
  float fx = x - xf, fy = y - yf, fz = z - zf;
  float gx0 = 1.f - fx, gy0 = 1.f - fy, gz0 = 1.f - fz;
  int i0 = (z0*128 + y0)*128 + x0;
  if ((unsigned)x0 < 127u && (unsigned)y0 < 127u && (unsigned)z0 < 127u){
    float* p = vol + i0;
    fadd(p,         gx0*gy0*gz0*val);
    fadd(p+1,       fx *gy0*gz0*val);
    fadd(p+128,     gx0*fy*gz0*val);
    fadd(p+129,     fx *fy*gz0*val);
    fadd(p+16384,   gx0*gy0*fz*val);
    fadd(p+16385,   fx *gy0*fz*val);
    fadd(p+16512,   gx0*fy*fz*val);
    fadd(p+16513,   fx *fy*fz*val);
    return;
  }
  bool vx0 = (unsigned)x0 < 128u, vx1 = (unsigned)(x0+1) < 128u;
  bool vy0 = (unsigned)y0 < 128u, vy1 = (unsigned)(y0+1) < 128u;
  bool vz0 = (unsigned)z0 < 128u, vz1 = (unsigned)(z0+1) < 128u;
  if (vz0){
    if (vy0){
      if (vx0) fadd(&vol[i0],     gx0*gy0*gz0*val);
      if (vx1) fadd(&vol[i0+1],   fx *gy0*gz0*val);
    }
    if (vy1){
      if (vx0) fadd(&vol[i0+128], gx0*fy*gz0*val);
      if (vx1) fadd(&vol[i0+129], fx *fy*gz0*val);
    }
  }
  if (vz1){
    int i1 = i0 + 16384;
    if (vy0){
      if (vx0) fadd(&vol[i1],     gx0*gy0*fz*val);
      if (vx1) fadd(&vol[i1+1],   fx *gy0*fz*val);
    }
    if (vy1){
      if (vx0) fadd(&vol[i1+128], gx0*fy*fz*val);
      if (vx1) fadd(&vol[i1+129], fx *fy*fz*val);
    }
  }
}

// ---------------- A: gather over 27 PSF taps (LDS prep + MLP) ----------------
__global__ void k_gather(const float* __restrict__ vol, const float* __restrict__ Rm,
                         const float* __restrict__ pw, const float* __restrict__ mask,
                         const float* __restrict__ ps, float* __restrict__ out,
                         int outStride, int outOff)
{
  int gid = blockIdx.x*256 + threadIdx.x;
  int n = gid >> 14;
  __shared__ float srm[12];
  __shared__ float sdof[27][3];
  __shared__ float spw[27];
  if (threadIdx.x < 12) srm[threadIdx.x] = Rm[n*12 + threadIdx.x];
  __syncthreads();
  if (threadIdx.x < 27){
    int k = threadIdx.x;
    float ox = (float)(k % 3) - 1.f;
    float oy = (float)((k/3) % 3) - 1.f;
    float oz = (float)(k/9) - 1.f;
    sdof[k][0] = srm[0]*ox + srm[1]*oy + srm[2]*oz;
    sdof[k][1] = srm[3]*ox + srm[4]*oy + srm[5]*oz;
    sdof[k][2] = srm[6]*ox + srm[7]*oy + srm[8]*oz;
    spw[k] = pw[k];
  }
  __syncthreads();
  int p = gid & 16383;
  int py = p >> 7, px = p & 127;
  float gx = (float)px - 63.5f, gy = (float)py - 63.5f;
  float bx = srm[0]*gx + srm[1]*gy + srm[9]  + 63.5f;
  float by = srm[3]*gx + srm[4]*gy + srm[10] + 63.5f;
  float bz = srm[6]*gx + srm[7]*gy + srm[11] + 63.5f;
  float acc = 0.f;
  for (int k = 0; k < 27; k += 3){
    float g0 = tri_gather(vol, bx+sdof[k  ][0], by+sdof[k  ][1], bz+sdof[k  ][2]);
    float g1 = tri_gather(vol, bx+sdof[k+1][0], by+sdof[k+1][1], bz+sdof[k+1][2]);
    float g2 = tri_gather(vol, bx+sdof[k+2][0], by+sdof[k+2][1], bz+sdof[k+2][2]);
    acc += spw[k]*g0 + spw[k+1]*g1 + spw[k+2]*g2;
  }
  float v = acc * mask[gid];
  if (ps) v *= ps[n];
  out[n*outStride + outOff + p] = v;
}

// ---------------- At: scatter v4 — LDS-privatized, HW fp atomics ----------------
__global__ __launch_bounds__(256, 2) void k_scatterp(
    float* __restrict__ volOut, const float* __restrict__ s,
    const float* __restrict__ Rm, const float* __restrict__ pw,
    const float* __restrict__ mask, const float* __restrict__ ps)
{
  __shared__ float srm[12];
  __shared__ float sdof[27][3];
  __shared__ float spw[27];
  __shared__ float sAcc[SCAP];

  int n  = blockIdx.x >> 6;
  int pt = blockIdx.x & 63;
  int px0 = (pt & 7) * 16;
  int py0 = (pt >> 3) * 16;
  int tid = threadIdx.x;

  if (tid < 12) srm[tid] = Rm[n*12 + tid];
  __syncthreads();
  if (tid < 27){
    int k = tid;
    float ox = (float)(k % 3) - 1.f;
    float oy = (float)((k/3) % 3) - 1.f;
    float oz = (float)(k/9) - 1.f;
    sdof[k][0] = srm[0]*ox + srm[1]*oy + srm[2]*oz;
    sdof[k][1] = srm[3]*ox + srm[4]*oy + srm[5]*oz;
    sdof[k][2] = srm[6]*ox + srm[7]*oy + srm[8]*oz;
    spw[k] = pw[k];
  }
  __syncthreads();

  int px = px0 + (tid & 15);
  int py = py0 + (tid >> 4);
  int p  = py*128 + px;
  float val = s[n*NPX + p] * mask[n*NPX + p];
  if (ps) val *= ps[n];

  float gx = (float)px - 63.5f, gy = (float)py - 63.5f;
  float bx = srm[0]*gx + srm[1]*gy + srm[9]  + 63.5f;
  float by = srm[3]*gx + srm[4]*gy + srm[10] + 63.5f;
  float bz = srm[6]*gx + srm[7]*gy + srm[11] + 63.5f;

  float gxa = (float)px0 - 63.5f, gxb = (float)(px0+15) - 63.5f;
  float gya = (float)py0 - 63.5f, gyb = (float)(py0+15) - 63.5f;
  int lo[3], hi[3];
  #pragma unroll
  for (int d = 0; d < 3; d++){
    float r0 = srm[d*3+0], r1 = srm[d*3+1];
    float ext = fabsf(r0) + fabsf(r1) + fabsf(srm[d*3+2]);
    float c = srm[9+d] + 63.5f;
    float mn = c + fminf(r0*gxa, r0*gxb) + fminf(r1*gya, r1*gyb) - ext;
    float mx = c + fmaxf(r0*gxa, r0*gxb) + fmaxf(r1*gya, r1*gyb) + ext;
    int l = (int)floorf(mn), h = (int)floorf(mx) + 1;
    lo[d] = (l < 0) ? 0 : l;
    hi[d] = (h > 127) ? 127 : h;
  }
  if (hi[0] < lo[0] || hi[1] < lo[1] || hi[2] < lo[2]) return;
  int Bx = hi[0]-lo[0]+1, By = hi[1]-lo[1]+1, Bz = hi[2]-lo[2]+1;
  int vol = Bx*By*Bz;
  int Bxy = Bx*By;

  if (vol <= SCAP){
    for (int i = tid; i < vol; i += 256) sAcc[i] = 0.f;
    __syncthreads();
    if (val != 0.f){
      for (int k = 0; k < 27; k++){
        float x = bx + sdof[k][0], y = by + sdof[k][1], z = bz + sdof[k][2];
        float xf = floorf(x), yf = floorf(y), zf = floorf(z);
        int x0 = (int)xf, y0 = (int)yf, z0 = (int)zf;
        float fx = x - xf, fy = y - yf, fz = z - zf;
        float gx0 = 1.f - fx, gy0 = 1.f - fy, gz0 = 1.f - fz;
        float v = spw[k]*val;
        int ix = x0 - lo[0], iy = y0 - lo[1], iz = z0 - lo[2];
        if (ix >= 0 && ix+1 < Bx && iy >= 0 && iy+1 < By && iz >= 0 && iz+1 < Bz){
          float* q = &sAcc[(iz*By + iy)*Bx + ix];
          fadd(q,          gx0*gy0*gz0*v);
          fadd(q+1,        fx *gy0*gz0*v);
          fadd(q+Bx,       gx0*fy*gz0*v);
          fadd(q+Bx+1,     fx *fy*gz0*v);
          fadd(q+Bxy,      gx0*gy0*fz*v);
          fadd(q+Bxy+1,    fx *gy0*fz*v);
          fadd(q+Bxy+Bx,   gx0*fy*fz*v);
          fadd(q+Bxy+Bx+1, fx *fy*fz*v);
        } else {
          #pragma unroll
          for (int c = 0; c < 8; c++){
            int dx = c & 1, dy = (c>>1) & 1, dz = c>>2;
            int xx = ix+dx, yy = iy+dy, zz = iz+dz;
            if ((unsigned)xx < (unsigned)Bx && (unsigned)yy < (unsigned)By && (unsigned)zz < (unsigned)Bz){
              float w = (dx ? fx : gx0) * (dy ? fy : gy0) * (dz ? fz : gz0);
              fadd(&sAcc[(zz*By + yy)*Bx + xx], w*v);
            }
          }
        }
      }
    }
    __syncthreads();
    for (int i = tid; i < vol; i += 256){
      float v = sAcc[i];
      if (v != 0.f){
        int x = i % Bx, r = i / Bx;
        int y = r % By, z = r / By;
        fadd(&volOut[((lo[2]+z)*128 + lo[1]+y)*128 + lo[0]+x], v);
      }
    }
  } else {
    if (val != 0.f){
      #pragma unroll 1
      for (int k = 0; k < 27; k++)
        tri_scatter(volOut, bx+sdof[k][0], by+sdof[k][1], bz+sdof[k][2], spw[k]*val);
    }
  }
}

// ---------------- tiled conv (NCHW fp32, LDS-staged, vertical-quad threads) ----------
// Block decode: spT (fast) -> batch-group (mid) -> coT (slow)  [XCD L2 reuse]
template<int K, int S, int TILE, int CC>
__global__ __launch_bounds__(256, 2) void k_convt(
    const float* __restrict__ in, const float* __restrict__ wt,
    const float* __restrict__ res, float* __restrict__ out,
    int Cin, int Hin, int Cout, int Hout,
    int pad, int relu, int nBG, int spTiles)
{
  constexpr int BPB  = 1024 / (TILE*TILE);
  constexpr int ITX  = (K==1) ? TILE : (TILE-1)*S + K;
  constexpr int ITP  = ITX | 1;
  constexpr int KK   = K*K;
  constexpr int PERB = TILE*TILE/4;
  constexpr int RS   = (K==1) ? 1 : S;
  constexpr int NIN  = (CC*ITX*ITX + PERB - 1)/PERB;
  constexpr int NWT  = (16*CC*KK + 255)/256;

  __shared__ float sIn[BPB*CC*ITX*ITP];
  __shared__ float sW[CC*KK*16];

  int tid = threadIdx.x;
  int bl  = tid / PERB;
  int t2  = tid % PERB;
  int tx  = t2 % TILE;
  int tyq = (t2 / TILE) * 4;

  int bid = blockIdx.x;
  int spT = bid % spTiles; bid /= spTiles;
  int bG  = bid % nBG;     bid /= nBG;
  int coT = bid;
  int b0  = bG * BPB;

  int tpr = Hout / TILE;
  int ox0 = (spT % tpr) * TILE;
  int oy0 = (spT / tpr) * TILE;
  int co0 = coT * 16;
  int ix0 = ox0*S - pad;
  int iy0 = oy0*S - pad;

  float acc[64];
  #pragma unroll
  for (int i = 0; i < 64; i++) acc[i] = 0.f;

  for (int ci0 = 0; ci0 < Cin; ci0 += CC){
    #pragma unroll
    for (int it = 0; it < NWT; it++){
      int i = tid + it*256;
      if (i < 16*CC*KK){
        int co = i / (CC*KK);
        int r  = i % (CC*KK);
        sW[r*16 + co] = wt[((size_t)(co0+co)*Cin + ci0 + r/KK)*KK + (r % KK)];
      }
    }
    #pragma unroll
    for (int it = 0; it < NIN; it++){
      int i = t2 + it*PERB;
      if (i < CC*ITX*ITX){
        int cc = i / (ITX*ITX);
        int r  = i % (ITX*ITX);
        int yy = r / ITX, xx = r % ITX;
        int gy = (K==1) ? iy0 + yy*S : iy0 + yy;
        int gx = (K==1) ? ix0 + xx*S : ix0 + xx;
        float v = 0.f;
        if ((unsigned)gy < (unsigned)Hin && (unsigned)gx < (unsigned)Hin)
          v = in[(((size_t)(b0+bl)*Cin + ci0+cc)*Hin + gy)*Hin + gx];
        sIn[((bl*CC + cc)*ITX + yy)*ITP + xx] = v;
      }
    }
    __syncthreads();

    #pragma unroll
    for (int cc = 0; cc < CC; cc++){
      const float* ip = &sIn[(bl*CC + cc)*ITX*ITP];
      #pragma unroll
      for (int ky = 0; ky < K; ky++){
        #pragma unroll
        for (int kx = 0; kx < K; kx++){
          int xi = (K==1) ? tx : tx*S + kx;
          int yb = (K==1) ? tyq : tyq*S + ky;
          float v0 = ip[(yb       )*ITP + xi];
          float v1 = ip[(yb +   RS)*ITP + xi];
          float v2 = ip[(yb + 2*RS)*ITP + xi];
          float v3 = ip[(yb + 3*RS)*ITP + xi];
          const float4* wv = (const float4*)&sW[(cc*KK + ky*K + kx)*16];
          #pragma unroll
          for (int g = 0; g < 4; g++){
            float4 w = wv[g];
            acc[(g*4+0)*4+0] += w.x*v0; acc[(g*4+0)*4+1] += w.x*v1;
            acc[(g*4+0)*4+2] += w.x*v2; acc[(g*4+0)*4+3] += w.x*v3;
            acc[(g*4+1)*4+0] += w.y*v0; acc[(g*4+1)*4+1] += w.y*v1;
            acc[(g*4+1)*4+2] += w.y*v2; acc[(g*4+1)*4+3] += w.y*v3;
            acc[(g*4+2)*4+0] += w.z*v0; acc[(g*4+2)*4+1] += w.z*v1;
            acc[(g*4+2)*4+2] += w.z*v2; acc[(g*4+2)*4+3] += w.z*v3;
            acc[(g*4+3)*4+0] += w.w*v0; acc[(g*4+3)*4+1] += w.w*v1;
            acc[(g*4+3)*4+2] += w.w*v2; acc[(g*4+3)*4+3] += w.w*v3;
          }
        }
      }
    }
    __syncthreads();
  }

  int b = b0 + bl;
  #pragma unroll
  for (int co = 0; co < 16; co++){
    size_t base = (((size_t)b*Cout + co0+co)*Hout + oy0 + tyq)*Hout + ox0 + tx;
    #pragma unroll
    for (int r = 0; r < 4; r++){
      float v = acc[co*4 + r];
      if (res) v += res[base + (size_t)r*Hout];
      if (relu) v = fmaxf(v, 0.f);
      out[base + (size_t)r*Hout] = v;
    }
  }
}

// ---------------- pool + transformer ----------------
__global__ void k_pool(const float* __restrict__ in, float* __restrict__ feat, int cnt)
{
  int gid = blockIdx.x*256 + threadIdx.x;
  if (gid >= cnt) return;
  const float* p = in + (size_t)gid*256;
  float s = 0.f;
  for (int i = 0; i < 256; i++) s += p[i];
  feat[gid] = s * (1.f/256.f);
}

__global__ void k_pe(const float* __restrict__ feat, const float* __restrict__ theta,
                     const float* __restrict__ idxin, const float* __restrict__ pos_w,
                     const float* __restrict__ pos_b, float* __restrict__ hs)
{
  int gid = blockIdx.x*256 + threadIdx.x;
  if (gid >= 64*256) return;
  int n = gid >> 8, d = gid & 255;
  float s = pos_b[d];
  #pragma unroll
  for (int j = 0; j < 6; j++) s += theta[n*6+j] * pos_w[j*256+d];
  #pragma unroll
  for (int j = 0; j < 2; j++) s += idxin[n*2+j] * pos_w[(6+j)*256+d];
  hs[gid] = feat[gid] + s;
}

__global__ void k_qkv(const float* __restrict__ hs, const float* __restrict__ wq,
                      const float* __restrict__ wk, const float* __restrict__ wv,
                      float* __restrict__ qkv)
{
  int gid = blockIdx.x*256 + threadIdx.x;
  if (gid >= 64*768) return;
  int n = gid / 768, m = gid % 768;
  int which = m >> 8, j = m & 255;
  const float* w = (which == 0) ? wq : (which == 1) ? wk : wv;
  const float* h = hs + n*256;
  float s = 0.f;
  for (int i = 0; i < 256; i++) s += h[i] * w[i*256 + j];
  qkv[which*16384 + n*256 + j] = s;
}

__global__ void k_attn(const float* __restrict__ qkv, float* __restrict__ aout)
{
  int h = blockIdx.x;
  int tid = threadIdx.x;
  __shared__ float sc[4096];
  const float* q  = qkv + h*64;
  const float* kk = qkv + 16384 + h*64;
  const float* v  = qkv + 32768 + h*64;
  for (int idx = tid; idx < 4096; idx += 256){
    int qi = idx >> 6, ki = idx & 63;
    float s = 0.f;
    for (int d = 0; d < 64; d++) s += q[qi*256+d] * kk[ki*256+d];
    sc[idx] = s * 0.125f;
  }
  __syncthreads();
  if (tid < 64){
    float mx = -1e30f;
    for (int k = 0; k < 64; k++) mx = fmaxf(mx, sc[tid*64+k]);
    float sum = 0.f;
    for (int k = 0; k < 64; k++){ float e = __expf(sc[tid*64+k]-mx); sc[tid*64+k] = e; sum += e; }
    float inv = 1.f/sum;
    for (int k = 0; k < 64; k++) sc[tid*64+k] *= inv;
  }
  __syncthreads();
  for (int idx = tid; idx < 4096; idx += 256){
    int qi = idx >> 6, d = idx & 63;
    float s = 0.f;
    for (int ki = 0; ki < 64; ki++) s += sc[qi*64+ki] * v[ki*256+d];
    aout[qi*256 + h*64 + d] = s;
  }
}

__global__ void k_proj_ln(const float* __restrict__ ain, const float* __restrict__ wo,
                          const float* __restrict__ g, const float* __restrict__ bb,
                          float* __restrict__ hs)
{
  int n = blockIdx.x, d = threadIdx.x;
  __shared__ float row[256];
  __shared__ float red[256];
  __shared__ float smean, svar;
  row[d] = ain[n*256+d];
  __syncthreads();
  float s = hs[n*256+d];
  for (int i = 0; i < 256; i++) s += row[i] * wo[i*256+d];
  red[d] = s; __syncthreads();
  for (int off = 128; off; off >>= 1){ if (d < off) red[d] += red[d+off]; __syncthreads(); }
  if (d == 0) smean = red[0] * (1.f/256.f);
  __syncthreads();
  float c = s - smean;
  red[d] = c*c; __syncthreads();
  for (int off = 128; off; off >>= 1){ if (d < off) red[d] += red[d+off]; __syncthreads(); }
  if (d == 0) svar = red[0] * (1.f/256.f);
  __syncthreads();
  hs[n*256+d] = c * rsqrtf(svar + 1e-5f) * g[d] + bb[d];
}

__global__ void k_ff1(const float* __restrict__ hs, const float* __restrict__ w,
                      const float* __restrict__ b, float* __restrict__ h1)
{
  int gid = blockIdx.x*256 + threadIdx.x;
  if (gid >= 64*512) return;
  int n = gid >> 9, j = gid & 511;
  float s = b[j];
  const float* h = hs + n*256;
  for (int i = 0; i < 256; i++) s += h[i] * w[i*512 + j];
  h1[gid] = fmaxf(s, 0.f);
}

__global__ void k_ff2_ln(const float* __restrict__ h1, const float* __restrict__ w,
                         const float* __restrict__ b, const float* __restrict__ g,
                         const float* __restrict__ bb, float* __restrict__ hs)
{
  int n = blockIdx.x, d = threadIdx.x;
  __shared__ float row[512];
  __shared__ float red[256];
  __shared__ float smean, svar;
  row[d] = h1[n*512+d];
  row[d+256] = h1[n*512+256+d];
  __syncthreads();
  float s = hs[n*256+d] + b[d];
  for (int i = 0; i < 512; i++) s += row[i] * w[i*256+d];
  red[d] = s; __syncthreads();
  for (int off = 128; off; off >>= 1){ if (d < off) red[d] += red[d+off]; __syncthreads(); }
  if (d == 0) smean = red[0] * (1.f/256.f);
  __syncthreads();
  float c = s - smean;
  red[d] = c*c; __syncthreads();
  for (int off = 128; off; off >>= 1){ if (d < off) red[d] += red[d+off]; __syncthreads(); }
  if (d == 0) svar = red[0] * (1.f/256.f);
  __syncthreads();
  hs[n*256+d] = c * rsqrtf(svar + 1e-5f) * g[d] + bb[d];
}

__global__ void k_head(const float* __restrict__ hs, const float* __restrict__ fcw,
                       const float* __restrict__ fcb, float* __restrict__ pvec,
                       float* __restrict__ outx)
{
  int n = threadIdx.x; // 64 threads
  float s = fcb[0];
  const float* h = hs + n*256;
  for (int i = 0; i < 256; i++) s += h[i] * fcw[i];
  __shared__ float xs[64];
  xs[n] = s;
  __syncthreads();
  float mx = -1e30f;
  for (int i = 0; i < 64; i++) mx = fmaxf(mx, xs[i]);
  float sum = 0.f;
  for (int i = 0; i < 64; i++) sum += __expf(xs[i]-mx);
  float val = __expf(s-mx)/sum * 64.f;
  val = fminf(val, 3.f);
  pvec[n] = val;
  outx[n] = val;
}

// ---------------- CG helpers ----------------
__global__ void k_dot(const float* __restrict__ a, const float* __restrict__ b,
                      float* __restrict__ scal, int slot, int n)
{
  int gid = blockIdx.x*blockDim.x + threadIdx.x;
  int stride = gridDim.x*blockDim.x;
  float s = 0.f;
  for (int i = gid; i < n; i += stride) s += a[i]*b[i];
  for (int off = 32; off; off >>= 1) s += __shfl_down(s, off, 64);
  __shared__ float wsum[4];
  int lane = threadIdx.x & 63, wv = threadIdx.x >> 6;
  if (lane == 0) wsum[wv] = s;
  __syncthreads();
  if (threadIdx.x == 0) atomicAdd(&scal[slot], wsum[0]+wsum[1]+wsum[2]+wsum[3]);
}

__global__ void k_div(float* scal, int so, int sa, int sb)
{
  if (threadIdx.x == 0 && blockIdx.x == 0) scal[so] = scal[sa] / scal[sb];
}

__global__ void k_rinit(const float* __restrict__ b, const float* __restrict__ A,
                        float* __restrict__ r, float* __restrict__ p)
{
  int gid = blockIdx.x*256 + threadIdx.x;
  if (gid < VN){ float v = b[gid] - A[gid]; r[gid] = v; p[gid] = v; }
}

__global__ void k_xr(float* __restrict__ x, const float* __restrict__ p,
                     float* __restrict__ r, const float* __restrict__ Ap,
                     const float* __restrict__ scal, int slot)
{
  int gid = blockIdx.x*256 + threadIdx.x;
  if (gid < VN){
    float a = scal[slot];
    x[gid] += a * p[gid];
    r[gid] -= a * Ap[gid];
  }
}

__global__ void k_pupd(float* __restrict__ p, const float* __restrict__ r,
                       const float* __restrict__ scal, int slot)
{
  int gid = blockIdx.x*256 + threadIdx.x;
  if (gid < VN){ float b = scal[slot]; p[gid] = r[gid] + b * p[gid]; }
}

__global__ void k_xonly(float* __restrict__ x, const float* __restrict__ p,
                        const float* __restrict__ scal, int slot)
{
  int gid = blockIdx.x*256 + threadIdx.x;
  if (gid < VN) x[gid] += scal[slot] * p[gid];
}

__global__ void k_final(const float* __restrict__ x, float* __restrict__ out)
{
  int gid = blockIdx.x*256 + threadIdx.x;
  if (gid < VN) out[gid] = fmaxf(x[gid], 0.f);
}

// ---------------- host launch ----------------
extern "C" void kernel_launch(void* const* d_in, const int* in_sizes, int n_in,
                              void* d_out, int out_size, void* d_ws, size_t ws_size,
                              hipStream_t stream)
{
  const float* theta      = (const float*)d_in[0];
  const float* transforms = (const float*)d_in[1];
  const float* slices     = (const float*)d_in[2];
  const float* volume     = (const float*)d_in[3];
  const float* psf        = (const float*)d_in[4];
  const float* idxv       = (const float*)d_in[5];

  char* wsp = (char*)d_ws;
  auto carve = [&](size_t bytes)->void*{
    void* r = (void*)wsp; wsp += (bytes + 255) & ~(size_t)255; return r;
  };
  float* scal = (float*)carve(16*4);
  float* Rm   = (float*)carve(768*4);
  float* pw   = (float*)carve(32*4);
  float* pvec = (float*)carve(64*4);
  float* feat = (float*)carve(16384*4);
  float* hs   = (float*)carve(16384*4);
  float* qkv  = (float*)carve(49152*4);
  float* aout = (float*)carve(16384*4);
  float* h1   = (float*)carve(32768*4);
  float* mask = (float*)carve((size_t)NSL*NPX*4);
  float* volA = (float*)carve((size_t)VN*4);

  size_t used  = (size_t)(wsp - (char*)d_ws);
  size_t avail = (ws_size > used) ? ws_size - used : 0;
  size_t cgU   = ((size_t)4*VN + NSL*NPX)*4;
  auto needU = [&](int cb)->size_t{
    size_t u = ((size_t)VN + 3*(size_t)cb*262144)*4;
    return (u > cgU) ? u : cgU;
  };
  int CB = 8;
  if (avail >= needU(64) + 4096) CB = 64;
  else if (avail >= needU(32) + 4096) CB = 32;

  size_t cbe = (size_t)CB*262144;
  float* U    = (float*)carve(needU(CB));
  float* z    = U;
  float* bufA = U + VN;
  float* bufB = bufA + cbe;
  float* bufC = bufB + cbe;
  float* bvol = U;
  float* rvol = U + VN;
  float* pvol = U + 2*(size_t)VN;
  float* Avol = U + 3*(size_t)VN;
  float* sscr = U + 4*(size_t)VN;

  hipMemsetAsync(scal, 0, 64, stream);
  k_prep<<<1, 64, 0, stream>>>(transforms, psf, Rm, pw);
  k_mask<<<4096, 256, 0, stream>>>(slices, mask);
  k_volcopy<<<8192, 256, 0, stream>>>(volume, volA);
  k_gather<<<4096, 256, 0, stream>>>(volA, Rm, pw, mask, nullptr, z, 2*NPX, NPX);
  k_copy0<<<4096, 256, 0, stream>>>(slices, z);

  const float* w6  = (const float*)d_in[6];
  const float* w7  = (const float*)d_in[7];
  const float* w8  = (const float*)d_in[8];
  const float* w9  = (const float*)d_in[9];
  const float* w10 = (const float*)d_in[10];
  const float* w11 = (const float*)d_in[11];
  const float* w12 = (const float*)d_in[12];
  const float* w13 = (const float*)d_in[13];
  const float* w14 = (const float*)d_in[14];

  for (int c = 0; c < 64/CB; c++){
    const float* zc = z + (size_t)c*CB*2*NPX;
    k_convt<7,2,32,2><<<CB*16, 256, 0, stream>>>(zc,  w6,  nullptr, bufA, 2,  128, 64,  64, 2, 1, CB, 4);
    k_convt<3,1,32,4><<<CB*16, 256, 0, stream>>>(bufA, w7,  nullptr, bufB, 64, 64,  64,  64, 1, 1, CB, 4);
    k_convt<3,1,32,4><<<CB*16, 256, 0, stream>>>(bufB, w8,  bufA,    bufC, 64, 64,  64,  64, 1, 1, CB, 4);
    k_convt<3,2,32,1><<<CB*8,  256, 0, stream>>>(bufC, w9,  nullptr, bufA, 64, 64,  128, 32, 0, 1, CB, 1);
    k_convt<1,2,32,2><<<CB*8,  256, 0, stream>>>(bufC, w11, nullptr, bufB, 64, 64,  128, 32, 0, 0, CB, 1);
    k_convt<3,1,32,4><<<CB*8,  256, 0, stream>>>(bufA, w10, bufB,    bufC, 128,32,  128, 32, 1, 1, CB, 1);
    k_convt<3,2,16,2><<<(CB/4)*16, 256, 0, stream>>>(bufC, w12, nullptr, bufA, 128, 32, 256, 16, 0, 1, CB/4, 1);
    k_convt<1,2,16,2><<<(CB/4)*16, 256, 0, stream>>>(bufC, w14, nullptr, bufB, 128, 32, 256, 16, 0, 0, CB/4, 1);
    k_convt<3,1,16,4><<<(CB/4)*16, 256, 0, stream>>>(bufA, w13, bufB,    bufC, 256, 16, 256, 16, 1, 1, CB/4, 1);
    k_pool<<<CB, 256, 0, stream>>>(bufC, feat + (size_t)c*CB*256, CB*256);
  }

  k_pe<<<64, 256, 0, stream>>>(feat, theta, idxv, (const float*)d_in[15], (const float*)d_in[16], hs);
  for (int l = 0; l < 4; l++){
    k_qkv<<<192, 256, 0, stream>>>(hs, (const float*)d_in[17] + (size_t)l*65536,
                                       (const float*)d_in[18] + (size_t)l*65536,
                                       (const float*)d_in[19] + (size_t)l*65536, qkv);
    k_attn<<<4, 256, 0, stream>>>(qkv, aout);
    k_proj_ln<<<64, 256, 0, stream>>>(aout, (const float*)d_in[20] + (size_t)l*65536,
                                      (const float*)d_in[21] + l*256, (const float*)d_in[22] + l*256, hs);
    k_ff1<<<128, 256, 0, stream>>>(hs, (const float*)d_in[23] + (size_t)l*131072,
                                   (const float*)d_in[24] + l*512, h1);
    k_ff2_ln<<<64, 256, 0, stream>>>(h1, (const float*)d_in[25] + (size_t)l*131072,
                                     (const float*)d_in[26] + l*256, (const float*)d_in[27] + l*256,
                                     (const float*)d_in[28] + l*256, hs);
  }
  k_head<<<1, 64, 0, stream>>>(hs, (const float*)d_in[29], (const float*)d_in[30], pvec,
                               (float*)d_out + VN);

  // ---- CG (union region now CG-owned) ----
  hipMemsetAsync(bvol, 0, (size_t)VN*4, stream);
  k_scatterp<<<4096, 256, 0, stream>>>(bvol, slices, Rm, pw, mask, pvec);      // b = At(slices*p)
  k_gather<<<4096, 256, 0, stream>>>(volA, Rm, pw, mask, pvec, sscr, NPX, 0);  // A(x0)*mask*p
  hipMemsetAsync(Avol, 0, (size_t)VN*4, stream);
  k_scatterp<<<4096, 256, 0, stream>>>(Avol, sscr, Rm, pw, mask, nullptr);     // AtA(x0)
  k_rinit<<<8192, 256, 0, stream>>>(bvol, Avol, rvol, pvol);
  k_dot<<<512, 256, 0, stream>>>(rvol, rvol, scal, 0, VN);         // rr0
  // iter 1
  k_gather<<<4096, 256, 0, stream>>>(pvol, Rm, pw, mask, pvec, sscr, NPX, 0);
  hipMemsetAsync(Avol, 0, (size_t)VN*4, stream);
  k_scatterp<<<4096, 256, 0, stream>>>(Avol, sscr, Rm, pw, mask, nullptr);
  k_dot<<<512, 256, 0, stream>>>(pvol, Avol, scal, 1, VN);         // pAp1
  k_div<<<1, 1, 0, stream>>>(scal, 2, 0, 1);                       // alpha1 = rr0/pAp1
  k_xr<<<8192, 256, 0, stream>>>(volA, pvol, rvol, Avol, scal, 2);
  k_dot<<<512, 256, 0, stream>>>(rvol, rvol, scal, 3, VN);         // rr1
  k_div<<<1, 1, 0, stream>>>(scal, 4, 3, 0);                       // beta = rr1/rr0
  k_pupd<<<8192, 256, 0, stream>>>(pvol, rvol, scal, 4);
  // iter 2
  k_gather<<<4096, 256, 0, stream>>>(pvol, Rm, pw, mask, pvec, sscr, NPX, 0);
  hipMemsetAsync(Avol, 0, (size_t)VN*4, stream);
  k_scatterp<<<4096, 256, 0, stream>>>(Avol, sscr, Rm, pw, mask, nullptr);
  k_dot<<<512, 256, 0, stream>>>(pvol, Avol, scal, 5, VN);         // pAp2
  k_div<<<1, 1, 0, stream>>>(scal, 6, 3, 5);                       // alpha2 = rr1/pAp2
  k_xonly<<<8192, 256, 0, stream>>>(volA, pvol, scal, 6);

  k_final<<<8192, 256, 0, stream>>>(volA, (float*)d_out);
}